// Round 16
// baseline (359.438 us; speedup 1.0000x reference)
//
#include <hip/hip_runtime.h>
#include <cstdint>
#include <cmath>

typedef _Float16 half_t;
typedef _Float16 h2 __attribute__((ext_vector_type(2)));
typedef _Float16 h8 __attribute__((ext_vector_type(8)));
typedef float f4 __attribute__((ext_vector_type(4)));

// ================= CSR build: bucketed radix partition by dst>>8 =================

__global__ __launch_bounds__(256) void csr_hist_kernel(const int* __restrict__ ei_dst,
                                                       int* __restrict__ hcnt,
                                                       int E, int B, int NB, int chunk) {
    __shared__ int hist[256];
    int t = threadIdx.x;
    hist[t] = 0;
    __syncthreads();
    int base = blockIdx.x * chunk;
    int lim = min(base + chunk, E);
    for (int e = base + t; e < lim; e += 256) {
        int dst = ei_dst[e];
        atomicAdd(&hist[dst >> 8], 1);
    }
    __syncthreads();
    if (t < B) hcnt[t * NB + blockIdx.x] = hist[t];
}

__global__ __launch_bounds__(256) void csr_bscan_kernel(int* __restrict__ hcnt,
                                                        int* __restrict__ btot, int NB) {
    __shared__ int sh[256];
    int b = blockIdx.x, t = threadIdx.x;
    int v = (t < NB) ? hcnt[b * NB + t] : 0;
    sh[t] = v;
    __syncthreads();
    for (int off = 1; off < 256; off <<= 1) {
        int u = (t >= off) ? sh[t - off] : 0;
        __syncthreads();
        sh[t] += u;
        __syncthreads();
    }
    if (t < NB) hcnt[b * NB + t] = sh[t] - v;
    if (t == 255) btot[b] = sh[255];
}

__global__ __launch_bounds__(256) void csr_ebase_kernel(const int* __restrict__ btot,
                                                        int* __restrict__ edge_base,
                                                        int* __restrict__ row_ptr,
                                                        int B, int E, int n) {
    __shared__ int sh[256];
    int t = threadIdx.x;
    int v = (t < B) ? btot[t] : 0;
    sh[t] = v;
    __syncthreads();
    for (int off = 1; off < 256; off <<= 1) {
        int u = (t >= off) ? sh[t - off] : 0;
        __syncthreads();
        sh[t] += u;
        __syncthreads();
    }
    if (t < B) edge_base[t] = sh[t] - v;
    if (t == 0) {
        edge_base[B] = E;
        row_ptr[n] = E;
    }
}

__global__ __launch_bounds__(256) void csr_part_kernel(const int* __restrict__ ei,
                                                       const int* __restrict__ hcnt,
                                                       const int* __restrict__ edge_base,
                                                       unsigned int* __restrict__ ebuf,
                                                       int E, int B, int NB, int chunk) {
    __shared__ int lcur[256];
    int t = threadIdx.x;
    if (t < B) lcur[t] = edge_base[t] + hcnt[t * NB + blockIdx.x];
    __syncthreads();
    int base = blockIdx.x * chunk;
    int lim = min(base + chunk, E);
    for (int e = base + t; e < lim; e += 256) {
        int src = ei[e];
        int dst = ei[E + e];
        int b = dst >> 8;
        int pos = atomicAdd(&lcur[b], 1);
        ebuf[pos] = ((unsigned int)(dst & 255) << 16) | (unsigned int)src;
    }
}

__global__ __launch_bounds__(256) void csr_fill_kernel(const unsigned int* __restrict__ ebuf,
                                                       const int* __restrict__ edge_base,
                                                       int* __restrict__ row_ptr,
                                                       float* __restrict__ dinv,
                                                       unsigned short* __restrict__ colidx,
                                                       int n) {
    __shared__ int cnt[256];
    __shared__ int sc[256];
    __shared__ int cur[256];
    int b = blockIdx.x;
    int t = threadIdx.x;
    int seg_beg = edge_base[b];
    int seg_end = edge_base[b + 1];
    cnt[t] = 0;
    __syncthreads();
    for (int e = seg_beg + t; e < seg_end; e += 256)
        atomicAdd(&cnt[ebuf[e] >> 16], 1);
    __syncthreads();
    sc[t] = cnt[t];
    __syncthreads();
    for (int off = 1; off < 256; off <<= 1) {
        int u = (t >= off) ? sc[t - off] : 0;
        __syncthreads();
        sc[t] += u;
        __syncthreads();
    }
    int excl = seg_beg + sc[t] - cnt[t];
    int node = (b << 8) + t;
    if (node < n) {
        row_ptr[node] = excl;
        dinv[node] = rsqrtf((float)cnt[t] + 1.0f);
    }
    cur[t] = excl;
    __syncthreads();
    for (int e = seg_beg + t; e < seg_end; e += 256) {
        unsigned int p = ebuf[e];
        int pos = atomicAdd(&cur[p >> 16], 1);
        colidx[pos] = (unsigned short)(p & 0xffff);
    }
}

// ---------------- conversions ----------------

__global__ void f2h_kernel(const float* __restrict__ x, half_t* __restrict__ xh, int total4) {
    int i = blockIdx.x * blockDim.x + threadIdx.x;
    if (i < total4) {
        float4 v = *(const float4*)&x[i * 4];
        half_t* p = xh + (size_t)i * 4;
        p[0] = (half_t)v.x; p[1] = (half_t)v.y; p[2] = (half_t)v.z; p[3] = (half_t)v.w;
    }
}

// ---------------- weight transposes (one launch). Wt[n][k] = W[k][n] ----------------

__global__ __launch_bounds__(256) void wtall_kernel(const float* __restrict__ W1,
                                                    const float* __restrict__ W2,
                                                    const float* __restrict__ W3,
                                                    const float* __restrict__ W4,
                                                    half_t* __restrict__ W1t,
                                                    half_t* __restrict__ W2t,
                                                    half_t* __restrict__ W3t,
                                                    half_t* __restrict__ W4t) {
    int idx = blockIdx.x * blockDim.x + threadIdx.x;
    if (idx < 32768) {
        int n = idx >> 7, k = idx & 127;
        W1t[idx] = (half_t)W1[k * 256 + n];
    } else if (idx < 65536) {
        int r = idx - 32768;
        int n = r >> 8, k = r & 255;
        W2t[r] = (half_t)W2[k * 128 + n];
    } else if (idx < 73728) {
        int r = idx - 65536;
        int n = r >> 7, k = r & 127;
        W3t[r] = (half_t)W3[k * 64 + n];
    } else if (idx < 77824) {
        int r = idx - 73728;
        int n = r >> 6, k = r & 63;
        W4t[r] = (n < 40) ? (half_t)W4[k * 40 + n] : (half_t)0.f;
    }
}

// ------- aggregation (fp16): out[d] = dinv[d]*(sum dinv[s]*in[s] + dinv[d]*in[d]) --------
// Wave per node, 4 nodes/block, masked unroll-8 (colidx padded by 16 zeros).
// ALWAYS gather from fp16 (round 13). No fused stats in 12.5k-block grids (round 12, G12).

__global__ __launch_bounds__(256) void aggh128_kernel(const half_t* __restrict__ in,
                                                      half_t* __restrict__ out,
                                                      const int* __restrict__ row_ptr,
                                                      const unsigned short* __restrict__ colidx,
                                                      const float* __restrict__ dinv, int n) {
    int node = blockIdx.x * 4 + (threadIdx.x >> 6);
    if (node >= n) return;
    int c = threadIdx.x & 63;
    float dv = dinv[node];
    h2 self = *(const h2*)(in + (size_t)node * 128 + 2 * c);
    float acc0 = dv * (float)self[0], acc1 = dv * (float)self[1];
    int beg = row_ptr[node], end = row_ptr[node + 1];
    for (int k = beg; k < end; k += 8) {
        int idx[8]; float w[8]; h2 v[8];
#pragma unroll
        for (int j = 0; j < 8; ++j) idx[j] = colidx[k + j];
#pragma unroll
        for (int j = 0; j < 8; ++j) w[j] = (k + j < end) ? dinv[idx[j]] : 0.f;
#pragma unroll
        for (int j = 0; j < 8; ++j) v[j] = *(const h2*)(in + (size_t)idx[j] * 128 + 2 * c);
#pragma unroll
        for (int j = 0; j < 8; ++j) {
            acc0 = fmaf(w[j], (float)v[j][0], acc0);
            acc1 = fmaf(w[j], (float)v[j][1], acc1);
        }
    }
    h2 r;
    r[0] = (half_t)(dv * acc0);
    r[1] = (half_t)(dv * acc1);
    *(h2*)(out + (size_t)node * 128 + 2 * c) = r;
}

__global__ __launch_bounds__(256) void aggh64_kernel(const half_t* __restrict__ in,
                                                     half_t* __restrict__ out,
                                                     const int* __restrict__ row_ptr,
                                                     const unsigned short* __restrict__ colidx,
                                                     const float* __restrict__ dinv, int n) {
    int node = blockIdx.x * 4 + (threadIdx.x >> 6);
    if (node >= n) return;
    int c = threadIdx.x & 63;
    float dv = dinv[node];
    float acc = dv * (float)in[(size_t)node * 64 + c];
    int beg = row_ptr[node], end = row_ptr[node + 1];
    for (int k = beg; k < end; k += 8) {
        int idx[8]; float w[8]; float v[8];
#pragma unroll
        for (int j = 0; j < 8; ++j) idx[j] = colidx[k + j];
#pragma unroll
        for (int j = 0; j < 8; ++j) w[j] = (k + j < end) ? dinv[idx[j]] : 0.f;
#pragma unroll
        for (int j = 0; j < 8; ++j) v[j] = (float)in[(size_t)idx[j] * 64 + c];
#pragma unroll
        for (int j = 0; j < 8; ++j) acc = fmaf(w[j], v[j], acc);
    }
    out[(size_t)node * 64 + c] = (half_t)(dv * acc);
}

// final layer: P4 padded [N,64] -> aggregate + b4 + log_softmax -> f32 out
__global__ __launch_bounds__(256) void aggsm64_kernel(const half_t* __restrict__ in,
                                                      float* __restrict__ out,
                                                      const int* __restrict__ row_ptr,
                                                      const unsigned short* __restrict__ colidx,
                                                      const float* __restrict__ dinv,
                                                      const float* __restrict__ b4, int n) {
    int node = blockIdx.x * 4 + (threadIdx.x >> 6);
    if (node >= n) return;
    int c = threadIdx.x & 31;  // lanes 32-63 mirror lanes 0-31
    float dv = dinv[node];
    h2 self = *(const h2*)(in + (size_t)node * 64 + 2 * c);
    float acc0 = dv * (float)self[0], acc1 = dv * (float)self[1];
    int beg = row_ptr[node], end = row_ptr[node + 1];
    for (int k = beg; k < end; k += 8) {
        int idx[8]; float w[8]; h2 v[8];
#pragma unroll
        for (int j = 0; j < 8; ++j) idx[j] = colidx[k + j];
#pragma unroll
        for (int j = 0; j < 8; ++j) w[j] = (k + j < end) ? dinv[idx[j]] : 0.f;
#pragma unroll
        for (int j = 0; j < 8; ++j) v[j] = *(const h2*)(in + (size_t)idx[j] * 64 + 2 * c);
#pragma unroll
        for (int j = 0; j < 8; ++j) {
            acc0 = fmaf(w[j], (float)v[j][0], acc0);
            acc1 = fmaf(w[j], (float)v[j][1], acc1);
        }
    }
    int col0 = 2 * c, col1 = 2 * c + 1;
    float z0 = (col0 < 40) ? (dv * acc0 + b4[col0]) : -INFINITY;
    float z1 = (col1 < 40) ? (dv * acc1 + b4[col1]) : -INFINITY;
    float m = fmaxf(z0, z1);
#pragma unroll
    for (int off = 16; off > 0; off >>= 1) m = fmaxf(m, __shfl_xor(m, off, 64));
    float e0 = (col0 < 40) ? expf(z0 - m) : 0.f;
    float e1 = (col1 < 40) ? expf(z1 - m) : 0.f;
    float s = e0 + e1;
#pragma unroll
    for (int off = 16; off > 0; off >>= 1) s += __shfl_xor(s, off, 64);
    float ls = logf(s);
    if (c < 20) {
        float2 r = make_float2(z0 - m - ls, z1 - m - ls);
        *(float2*)(out + (size_t)node * 40 + 2 * c) = r;
    }
}

// ---------------- MFMA GEMM v5: col-split LDS weights + bank-pad + BNC (no stats) -------
// Fused stats REMOVED: its epilogue's 262K device-scope atomics cost ~95ns each (~12us,
// calibrated by round 12's 3.2M-atomic 300us blowup). Stats now partial-store based.

template <int K, int NT, bool BNC>
__global__ __launch_bounds__(256) void mgemm_kernel(const half_t* __restrict__ A,
                                                    const half_t* __restrict__ Wt,  // [cols][K]
                                                    const float* __restrict__ bn_stats,
                                                    const float* __restrict__ g,
                                                    const float* __restrict__ be,
                                                    const float* __restrict__ pa,
                                                    half_t* __restrict__ C,
                                                    int M, int Nc, int nTiles) {
    constexpr int NR = NT * 16;      // cols staged per block
    constexpr int CH = K / 8;        // 16B chunks per col (power of 2)
    constexpr int LOG_CH = (CH == 8) ? 3 : (CH == 16 ? 4 : 5);
    constexpr int CSTRIDE = NR + 1;  // chunk stride in h8 units (+16B bank pad)
    __shared__ half_t wlds[CH * CSTRIDE * 8];
    __shared__ float sc_l[K], of_l[K];

    int t = threadIdx.x;
    int colbase = blockIdx.y * NR;
    for (int idx = t; idx < NR * CH; idx += 256) {
        int row = idx >> LOG_CH;
        int c = idx & (CH - 1);
        *(h8*)(wlds + ((size_t)c * CSTRIDE + row) * 8) =
            *(const h8*)(Wt + (size_t)(colbase + row) * K + c * 8);
    }
    if (BNC && t < K) {
        float inv_n = 1.0f / (float)M;
        float mean = bn_stats[t] * inv_n;
        float var = bn_stats[256 + t] * inv_n - mean * mean;
        float rstd = rsqrtf(var + 1e-5f);
        float s = g[t] * rstd;
        sc_l[t] = s;
        of_l[t] = be[t] - mean * s;
    }
    int wave = t >> 6;
    int lane = t & 63;
    int l16 = lane & 15, kgrp = lane >> 4;
    float alpha = BNC ? pa[0] : 0.f;
    __syncthreads();

    for (int tile = blockIdx.x; tile < nTiles; tile += gridDim.x) {
        int r0 = tile * 64 + wave * 16;
        int arow = r0 + l16;
        bool rowok = (arow < M);
        const half_t* Ap = A + (size_t)arow * K + kgrp * 8;
        h8 af[K / 32];
#pragma unroll
        for (int kk = 0; kk < K / 32; ++kk) {
            h8 v;
            if (rowok) {
                v = *(const h8*)(Ap + kk * 32);
            } else {
#pragma unroll
                for (int j = 0; j < 8; ++j) v[j] = (half_t)0.f;
            }
            if (BNC) {
                int kb = kk * 32 + kgrp * 8;
#pragma unroll
                for (int j = 0; j < 8; ++j) {
                    float u = (float)v[j] * sc_l[kb + j] + of_l[kb + j];
                    u = (u >= 0.f) ? u : alpha * u;
                    v[j] = (half_t)u;
                }
            }
            af[kk] = v;
        }

        for (int nt = 0; nt < NT; ++nt) {
            f4 acc = {0.f, 0.f, 0.f, 0.f};
#pragma unroll
            for (int kk = 0; kk < K / 32; ++kk) {
                h8 bf = *(const h8*)(wlds +
                                     ((size_t)(kk * 4 + kgrp) * CSTRIDE + nt * 16 + l16) * 8);
                acc = __builtin_amdgcn_mfma_f32_16x16x32_f16(af[kk], bf, acc, 0, 0, 0);
            }
            int col = colbase + nt * 16 + l16;
            if (col < Nc) {
#pragma unroll
                for (int j = 0; j < 4; ++j) {
                    int row = r0 + kgrp * 4 + j;
                    if (row < M) C[(size_t)row * Nc + col] = (half_t)acc[j];
                }
            }
        }
    }
}

// ---------------- BatchNorm stats: per-block PARTIAL STORES (no global atomics) --------
// Each block writes its reduced 2F values to part[block][2F] with plain coalesced stores;
// statsred sums the partials. Eliminates the ~95ns-per-atomic serial tax (round 12/15).

template <int F>
__global__ __launch_bounds__(256) void stats2_kernel(const half_t* __restrict__ z,
                                                     float* __restrict__ part, int n) {
    constexpr int CB = F / 8;
    constexpr int RG = 256 / CB;
    __shared__ float red[256][16];
    int t = threadIdx.x;
    int cb = t % CB;
    int rg = t / CB;
    float sm[8], sq[8];
#pragma unroll
    for (int j = 0; j < 8; ++j) { sm[j] = 0.f; sq[j] = 0.f; }
    for (int r = blockIdx.x * RG + rg; r < n; r += gridDim.x * RG) {
        h8 v = *(const h8*)(z + (size_t)r * F + cb * 8);
#pragma unroll
        for (int j = 0; j < 8; ++j) {
            float f = (float)v[j];
            sm[j] += f;
            sq[j] = fmaf(f, f, sq[j]);
        }
    }
#pragma unroll
    for (int j = 0; j < 8; ++j) { red[t][j] = sm[j]; red[t][8 + j] = sq[j]; }
    __syncthreads();
    for (int o = t; o < 2 * F; o += 256) {
        int c = o % F, kind = o / F;
        int cbo = c >> 3, ci = (c & 7) + kind * 8;
        float v = 0.f;
#pragma unroll
        for (int g = 0; g < RG; ++g) v += red[g * CB + cbo][ci];
        part[(size_t)blockIdx.x * (2 * F) + o] = v;
    }
}

// reduce nb partials of 2F values -> sums[kind*256 + c]. One block, 2F threads.
template <int F>
__global__ void statsred_kernel(const float* __restrict__ part, float* __restrict__ sums,
                                int nb) {
    int o = threadIdx.x;
    if (o >= 2 * F) return;
    float s0 = 0.f, s1 = 0.f, s2 = 0.f, s3 = 0.f;
    int b = 0;
    for (; b + 3 < nb; b += 4) {
        s0 += part[(size_t)b * 2 * F + o];
        s1 += part[(size_t)(b + 1) * 2 * F + o];
        s2 += part[(size_t)(b + 2) * 2 * F + o];
        s3 += part[(size_t)(b + 3) * 2 * F + o];
    }
    for (; b < nb; ++b) s0 += part[(size_t)b * 2 * F + o];
    float s = (s0 + s1) + (s2 + s3);
    int kind = o >= F;
    int c = o - kind * F;
    sums[kind * 256 + c] = s;
}

// ---------------- launch ----------------

extern "C" void kernel_launch(void* const* d_in, const int* in_sizes, int n_in,
                              void* d_out, int out_size, void* d_ws, size_t ws_size,
                              hipStream_t stream) {
    const float* x   = (const float*)d_in[0];
    const int*   ei  = (const int*)d_in[1];
    const float* W1  = (const float*)d_in[2];
    const float* g1  = (const float*)d_in[4];
    const float* be1 = (const float*)d_in[5];
    const float* W2  = (const float*)d_in[6];
    const float* g2  = (const float*)d_in[8];
    const float* be2 = (const float*)d_in[9];
    const float* W3  = (const float*)d_in[10];
    const float* g3  = (const float*)d_in[12];
    const float* be3 = (const float*)d_in[13];
    const float* W4  = (const float*)d_in[14];
    const float* b4  = (const float*)d_in[15];
    const float* pa  = (const float*)d_in[16];
    // b1,b2,b3 dropped: constants before BatchNorm cancel exactly in mean subtraction.

    int N = in_sizes[0] / 128;
    int E = in_sizes[1] / 2;
    int B = (N + 255) >> 8;
    int chunk = (((E + 255) / 256) + 255) & ~255;
    int NB = (E + chunk - 1) / chunk;

    char* ws = (char*)d_ws;
    size_t off = 0;
    auto carve = [&](size_t bytes) -> char* {
        char* p = ws + off;
        off += (bytes + 255) & ~(size_t)255;
        return p;
    };
    float*          dinv      = (float*)carve((size_t)N * 4);
    int*            row_ptr   = (int*)carve((size_t)(N + 1) * 4);
    int*            hcnt      = (int*)carve((size_t)B * NB * 4);
    int*            btot      = (int*)carve((size_t)B * 4);
    int*            edge_base = (int*)carve((size_t)(B + 1) * 4);
    unsigned int*   ebuf      = (unsigned int*)carve((size_t)E * 4);
    unsigned short* colidx    = (unsigned short*)carve((size_t)(E + 16) * 2);
    float*          stats     = (float*)carve(3 * 512 * 4);
    float*          spart     = (float*)carve((size_t)512 * 512 * 4);  // stats partials
    half_t* W1t = (half_t*)carve((size_t)256 * 128 * 2);
    half_t* W2t = (half_t*)carve((size_t)128 * 256 * 2);
    half_t* W3t = (half_t*)carve((size_t)64 * 128 * 2);
    half_t* W4t = (half_t*)carve((size_t)64 * 64 * 2);
    half_t* hA  = (half_t*)carve((size_t)N * 256 * 2);  // Z1
    half_t* hB  = (half_t*)carve((size_t)N * 128 * 2);  // xh, P2
    half_t* hC  = (half_t*)carve((size_t)N * 128 * 2);  // P1, Z2
    half_t* hD1 = (half_t*)carve((size_t)N * 64 * 2);   // P3
    half_t* hD2 = (half_t*)carve((size_t)N * 64 * 2);   // Z3
    half_t* hE  = (half_t*)carve((size_t)N * 64 * 2);   // P4 padded
    (void)n_in; (void)out_size; (void)ws_size;

    // only the colidx pad needs zeroing now (stats written, not accumulated)
    hipMemsetAsync(colidx + E, 0, 32, stream);

    // CSR build
    csr_hist_kernel<<<NB, 256, 0, stream>>>(ei + E, hcnt, E, B, NB, chunk);
    csr_bscan_kernel<<<B, 256, 0, stream>>>(hcnt, btot, NB);
    csr_ebase_kernel<<<1, 256, 0, stream>>>(btot, edge_base, row_ptr, B, E, N);
    csr_part_kernel<<<NB, 256, 0, stream>>>(ei, hcnt, edge_base, ebuf, E, B, NB, chunk);
    csr_fill_kernel<<<B, 256, 0, stream>>>(ebuf, edge_base, row_ptr, dinv, colidx, N);

    wtall_kernel<<<(77824 + 255) / 256, 256, 0, stream>>>(W1, W2, W3, W4, W1t, W2t, W3t, W4t);

    int nTiles = (N + 63) / 64;
    int ab = (N + 3) / 4;

    // L1: x->fp16, aggregate, GEMM1 (col-split y=2), then Z1 stats (partials + reduce)
    f2h_kernel<<<(N * 128 / 4 + 255) / 256, 256, 0, stream>>>(x, hB, N * 128 / 4);
    aggh128_kernel<<<ab, 256, 0, stream>>>(hB, hC, row_ptr, colidx, dinv, N);
    mgemm_kernel<128, 8, false><<<dim3(512, 2), 256, 0, stream>>>(
        hC, W1t, nullptr, nullptr, nullptr, nullptr, hA, N, 256, nTiles);
    stats2_kernel<256><<<512, 256, 0, stream>>>(hA, spart, N);
    statsred_kernel<256><<<1, 512, 0, stream>>>(spart, stats, 512);

    // L2: GEMM2 (BN1+PReLU coeffs in-kernel) -> P2, aggregate -> Z2, stats
    mgemm_kernel<256, 4, true><<<dim3(512, 2), 256, 0, stream>>>(
        hA, W2t, stats, g1, be1, pa, hB, N, 128, nTiles);
    aggh128_kernel<<<ab, 256, 0, stream>>>(hB, hC, row_ptr, colidx, dinv, N);
    stats2_kernel<128><<<512, 256, 0, stream>>>(hC, spart, N);
    statsred_kernel<128><<<1, 256, 0, stream>>>(spart, stats + 512, 512);

    // L3: GEMM3 (BN2 fused) -> P3, aggregate -> Z3, stats
    mgemm_kernel<128, 4, true><<<nTiles, 256, 0, stream>>>(
        hC, W3t, stats + 512, g2, be2, pa, hD1, N, 64, nTiles);
    aggh64_kernel<<<ab, 256, 0, stream>>>(hD1, hD2, row_ptr, colidx, dinv, N);
    stats2_kernel<64><<<512, 256, 0, stream>>>(hD2, spart, N);
    statsred_kernel<64><<<1, 128, 0, stream>>>(spart, stats + 1024, 512);

    // L4: GEMM4 (BN3 fused) -> P4 padded, aggregate + b4 + log_softmax -> out
    mgemm_kernel<64, 4, true><<<nTiles, 256, 0, stream>>>(
        hD2, W4t, stats + 1024, g3, be3, pa, hE, N, 64, nTiles);
    aggsm64_kernel<<<ab, 256, 0, stream>>>(hE, (float*)d_out, row_ptr, colidx, dinv, b4, N);
}

// Round 17
// 283.654 us; speedup vs baseline: 1.2672x; 1.2672x over previous
//
#include <hip/hip_runtime.h>
#include <cstdint>
#include <cmath>

typedef _Float16 half_t;
typedef _Float16 h2 __attribute__((ext_vector_type(2)));
typedef _Float16 h8 __attribute__((ext_vector_type(8)));
typedef float f4 __attribute__((ext_vector_type(4)));

// ================= CSR build: bucketed radix partition by dst>>8 =================

__global__ __launch_bounds__(256) void csr_hist_kernel(const int* __restrict__ ei_dst,
                                                       int* __restrict__ hcnt,
                                                       int E, int B, int NB, int chunk) {
    __shared__ int hist[256];
    int t = threadIdx.x;
    hist[t] = 0;
    __syncthreads();
    int base = blockIdx.x * chunk;
    int lim = min(base + chunk, E);
    for (int e = base + t; e < lim; e += 256) {
        int dst = ei_dst[e];
        atomicAdd(&hist[dst >> 8], 1);
    }
    __syncthreads();
    if (t < B) hcnt[t * NB + blockIdx.x] = hist[t];
}

__global__ __launch_bounds__(256) void csr_bscan_kernel(int* __restrict__ hcnt,
                                                        int* __restrict__ btot, int NB) {
    __shared__ int sh[256];
    int b = blockIdx.x, t = threadIdx.x;
    int v = (t < NB) ? hcnt[b * NB + t] : 0;
    sh[t] = v;
    __syncthreads();
    for (int off = 1; off < 256; off <<= 1) {
        int u = (t >= off) ? sh[t - off] : 0;
        __syncthreads();
        sh[t] += u;
        __syncthreads();
    }
    if (t < NB) hcnt[b * NB + t] = sh[t] - v;
    if (t == 255) btot[b] = sh[255];
}

__global__ __launch_bounds__(256) void csr_ebase_kernel(const int* __restrict__ btot,
                                                        int* __restrict__ edge_base,
                                                        int* __restrict__ row_ptr,
                                                        int B, int E, int n) {
    __shared__ int sh[256];
    int t = threadIdx.x;
    int v = (t < B) ? btot[t] : 0;
    sh[t] = v;
    __syncthreads();
    for (int off = 1; off < 256; off <<= 1) {
        int u = (t >= off) ? sh[t - off] : 0;
        __syncthreads();
        sh[t] += u;
        __syncthreads();
    }
    if (t < B) edge_base[t] = sh[t] - v;
    if (t == 0) {
        edge_base[B] = E;
        row_ptr[n] = E;
    }
}

__global__ __launch_bounds__(256) void csr_part_kernel(const int* __restrict__ ei,
                                                       const int* __restrict__ hcnt,
                                                       const int* __restrict__ edge_base,
                                                       unsigned int* __restrict__ ebuf,
                                                       int E, int B, int NB, int chunk) {
    __shared__ int lcur[256];
    int t = threadIdx.x;
    if (t < B) lcur[t] = edge_base[t] + hcnt[t * NB + blockIdx.x];
    __syncthreads();
    int base = blockIdx.x * chunk;
    int lim = min(base + chunk, E);
    for (int e = base + t; e < lim; e += 256) {
        int src = ei[e];
        int dst = ei[E + e];
        int b = dst >> 8;
        int pos = atomicAdd(&lcur[b], 1);
        ebuf[pos] = ((unsigned int)(dst & 255) << 16) | (unsigned int)src;
    }
}

__global__ __launch_bounds__(256) void csr_fill_kernel(const unsigned int* __restrict__ ebuf,
                                                       const int* __restrict__ edge_base,
                                                       int* __restrict__ row_ptr,
                                                       float* __restrict__ dinv,
                                                       unsigned short* __restrict__ colidx,
                                                       int n) {
    __shared__ int cnt[256];
    __shared__ int sc[256];
    __shared__ int cur[256];
    int b = blockIdx.x;
    int t = threadIdx.x;
    int seg_beg = edge_base[b];
    int seg_end = edge_base[b + 1];
    cnt[t] = 0;
    __syncthreads();
    for (int e = seg_beg + t; e < seg_end; e += 256)
        atomicAdd(&cnt[ebuf[e] >> 16], 1);
    __syncthreads();
    sc[t] = cnt[t];
    __syncthreads();
    for (int off = 1; off < 256; off <<= 1) {
        int u = (t >= off) ? sc[t - off] : 0;
        __syncthreads();
        sc[t] += u;
        __syncthreads();
    }
    int excl = seg_beg + sc[t] - cnt[t];
    int node = (b << 8) + t;
    if (node < n) {
        row_ptr[node] = excl;
        dinv[node] = rsqrtf((float)cnt[t] + 1.0f);
    }
    cur[t] = excl;
    __syncthreads();
    for (int e = seg_beg + t; e < seg_end; e += 256) {
        unsigned int p = ebuf[e];
        int pos = atomicAdd(&cur[p >> 16], 1);
        colidx[pos] = (unsigned short)(p & 0xffff);
    }
}

// ---------------- conversions ----------------

__global__ void f2h_kernel(const float* __restrict__ x, half_t* __restrict__ xh, int total4) {
    int i = blockIdx.x * blockDim.x + threadIdx.x;
    if (i < total4) {
        float4 v = *(const float4*)&x[i * 4];
        half_t* p = xh + (size_t)i * 4;
        p[0] = (half_t)v.x; p[1] = (half_t)v.y; p[2] = (half_t)v.z; p[3] = (half_t)v.w;
    }
}

// ---------------- weight transposes (one launch). Wt[n][k] = W[k][n] ----------------

__global__ __launch_bounds__(256) void wtall_kernel(const float* __restrict__ W1,
                                                    const float* __restrict__ W2,
                                                    const float* __restrict__ W3,
                                                    const float* __restrict__ W4,
                                                    half_t* __restrict__ W1t,
                                                    half_t* __restrict__ W2t,
                                                    half_t* __restrict__ W3t,
                                                    half_t* __restrict__ W4t) {
    int idx = blockIdx.x * blockDim.x + threadIdx.x;
    if (idx < 32768) {
        int n = idx >> 7, k = idx & 127;
        W1t[idx] = (half_t)W1[k * 256 + n];
    } else if (idx < 65536) {
        int r = idx - 32768;
        int n = r >> 8, k = r & 255;
        W2t[r] = (half_t)W2[k * 128 + n];
    } else if (idx < 73728) {
        int r = idx - 65536;
        int n = r >> 7, k = r & 127;
        W3t[r] = (half_t)W3[k * 64 + n];
    } else if (idx < 77824) {
        int r = idx - 73728;
        int n = r >> 6, k = r & 63;
        W4t[r] = (n < 40) ? (half_t)W4[k * 40 + n] : (half_t)0.f;
    }
}

// ------- aggregation (fp16): out[d] = dinv[d]*(sum dinv[s]*in[s] + dinv[d]*in[d]) --------
// Wave per node, 4 nodes/block, masked unroll-8 (colidx padded by 16 zeros).
// ALWAYS gather from fp16 (round 13). No fused stats in 12.5k-block grids (round 12, G12).

__global__ __launch_bounds__(256) void aggh128_kernel(const half_t* __restrict__ in,
                                                      half_t* __restrict__ out,
                                                      const int* __restrict__ row_ptr,
                                                      const unsigned short* __restrict__ colidx,
                                                      const float* __restrict__ dinv, int n) {
    int node = blockIdx.x * 4 + (threadIdx.x >> 6);
    if (node >= n) return;
    int c = threadIdx.x & 63;
    float dv = dinv[node];
    h2 self = *(const h2*)(in + (size_t)node * 128 + 2 * c);
    float acc0 = dv * (float)self[0], acc1 = dv * (float)self[1];
    int beg = row_ptr[node], end = row_ptr[node + 1];
    for (int k = beg; k < end; k += 8) {
        int idx[8]; float w[8]; h2 v[8];
#pragma unroll
        for (int j = 0; j < 8; ++j) idx[j] = colidx[k + j];
#pragma unroll
        for (int j = 0; j < 8; ++j) w[j] = (k + j < end) ? dinv[idx[j]] : 0.f;
#pragma unroll
        for (int j = 0; j < 8; ++j) v[j] = *(const h2*)(in + (size_t)idx[j] * 128 + 2 * c);
#pragma unroll
        for (int j = 0; j < 8; ++j) {
            acc0 = fmaf(w[j], (float)v[j][0], acc0);
            acc1 = fmaf(w[j], (float)v[j][1], acc1);
        }
    }
    h2 r;
    r[0] = (half_t)(dv * acc0);
    r[1] = (half_t)(dv * acc1);
    *(h2*)(out + (size_t)node * 128 + 2 * c) = r;
}

__global__ __launch_bounds__(256) void aggh64_kernel(const half_t* __restrict__ in,
                                                     half_t* __restrict__ out,
                                                     const int* __restrict__ row_ptr,
                                                     const unsigned short* __restrict__ colidx,
                                                     const float* __restrict__ dinv, int n) {
    int node = blockIdx.x * 4 + (threadIdx.x >> 6);
    if (node >= n) return;
    int c = threadIdx.x & 63;
    float dv = dinv[node];
    float acc = dv * (float)in[(size_t)node * 64 + c];
    int beg = row_ptr[node], end = row_ptr[node + 1];
    for (int k = beg; k < end; k += 8) {
        int idx[8]; float w[8]; float v[8];
#pragma unroll
        for (int j = 0; j < 8; ++j) idx[j] = colidx[k + j];
#pragma unroll
        for (int j = 0; j < 8; ++j) w[j] = (k + j < end) ? dinv[idx[j]] : 0.f;
#pragma unroll
        for (int j = 0; j < 8; ++j) v[j] = (float)in[(size_t)idx[j] * 64 + c];
#pragma unroll
        for (int j = 0; j < 8; ++j) acc = fmaf(w[j], v[j], acc);
    }
    out[(size_t)node * 64 + c] = (half_t)(dv * acc);
}

// final layer: P4 padded [N,64] -> aggregate + b4 + log_softmax -> f32 out
__global__ __launch_bounds__(256) void aggsm64_kernel(const half_t* __restrict__ in,
                                                      float* __restrict__ out,
                                                      const int* __restrict__ row_ptr,
                                                      const unsigned short* __restrict__ colidx,
                                                      const float* __restrict__ dinv,
                                                      const float* __restrict__ b4, int n) {
    int node = blockIdx.x * 4 + (threadIdx.x >> 6);
    if (node >= n) return;
    int c = threadIdx.x & 31;  // lanes 32-63 mirror lanes 0-31
    float dv = dinv[node];
    h2 self = *(const h2*)(in + (size_t)node * 64 + 2 * c);
    float acc0 = dv * (float)self[0], acc1 = dv * (float)self[1];
    int beg = row_ptr[node], end = row_ptr[node + 1];
    for (int k = beg; k < end; k += 8) {
        int idx[8]; float w[8]; h2 v[8];
#pragma unroll
        for (int j = 0; j < 8; ++j) idx[j] = colidx[k + j];
#pragma unroll
        for (int j = 0; j < 8; ++j) w[j] = (k + j < end) ? dinv[idx[j]] : 0.f;
#pragma unroll
        for (int j = 0; j < 8; ++j) v[j] = *(const h2*)(in + (size_t)idx[j] * 64 + 2 * c);
#pragma unroll
        for (int j = 0; j < 8; ++j) {
            acc0 = fmaf(w[j], (float)v[j][0], acc0);
            acc1 = fmaf(w[j], (float)v[j][1], acc1);
        }
    }
    int col0 = 2 * c, col1 = 2 * c + 1;
    float z0 = (col0 < 40) ? (dv * acc0 + b4[col0]) : -INFINITY;
    float z1 = (col1 < 40) ? (dv * acc1 + b4[col1]) : -INFINITY;
    float m = fmaxf(z0, z1);
#pragma unroll
    for (int off = 16; off > 0; off >>= 1) m = fmaxf(m, __shfl_xor(m, off, 64));
    float e0 = (col0 < 40) ? expf(z0 - m) : 0.f;
    float e1 = (col1 < 40) ? expf(z1 - m) : 0.f;
    float s = e0 + e1;
#pragma unroll
    for (int off = 16; off > 0; off >>= 1) s += __shfl_xor(s, off, 64);
    float ls = logf(s);
    if (c < 20) {
        float2 r = make_float2(z0 - m - ls, z1 - m - ls);
        *(float2*)(out + (size_t)node * 40 + 2 * c) = r;
    }
}

// ---------------- MFMA GEMM v5: col-split LDS weights + bank-pad + BNC (no stats) -------
// No fused STATS (round 16 confirmed: GEMM1 50.6 -> <39us without it).

template <int K, int NT, bool BNC>
__global__ __launch_bounds__(256) void mgemm_kernel(const half_t* __restrict__ A,
                                                    const half_t* __restrict__ Wt,  // [cols][K]
                                                    const float* __restrict__ bn_stats,
                                                    const float* __restrict__ g,
                                                    const float* __restrict__ be,
                                                    const float* __restrict__ pa,
                                                    half_t* __restrict__ C,
                                                    int M, int Nc, int nTiles) {
    constexpr int NR = NT * 16;
    constexpr int CH = K / 8;
    constexpr int LOG_CH = (CH == 8) ? 3 : (CH == 16 ? 4 : 5);
    constexpr int CSTRIDE = NR + 1;  // +16B bank pad (round 15: conflicts 1.8M -> 524K)
    __shared__ half_t wlds[CH * CSTRIDE * 8];
    __shared__ float sc_l[K], of_l[K];

    int t = threadIdx.x;
    int colbase = blockIdx.y * NR;
    for (int idx = t; idx < NR * CH; idx += 256) {
        int row = idx >> LOG_CH;
        int c = idx & (CH - 1);
        *(h8*)(wlds + ((size_t)c * CSTRIDE + row) * 8) =
            *(const h8*)(Wt + (size_t)(colbase + row) * K + c * 8);
    }
    if (BNC && t < K) {
        float inv_n = 1.0f / (float)M;
        float mean = bn_stats[t] * inv_n;
        float var = bn_stats[256 + t] * inv_n - mean * mean;
        float rstd = rsqrtf(var + 1e-5f);
        float s = g[t] * rstd;
        sc_l[t] = s;
        of_l[t] = be[t] - mean * s;
    }
    int wave = t >> 6;
    int lane = t & 63;
    int l16 = lane & 15, kgrp = lane >> 4;
    float alpha = BNC ? pa[0] : 0.f;
    __syncthreads();

    for (int tile = blockIdx.x; tile < nTiles; tile += gridDim.x) {
        int r0 = tile * 64 + wave * 16;
        int arow = r0 + l16;
        bool rowok = (arow < M);
        const half_t* Ap = A + (size_t)arow * K + kgrp * 8;
        h8 af[K / 32];
#pragma unroll
        for (int kk = 0; kk < K / 32; ++kk) {
            h8 v;
            if (rowok) {
                v = *(const h8*)(Ap + kk * 32);
            } else {
#pragma unroll
                for (int j = 0; j < 8; ++j) v[j] = (half_t)0.f;
            }
            if (BNC) {
                int kb = kk * 32 + kgrp * 8;
#pragma unroll
                for (int j = 0; j < 8; ++j) {
                    float u = (float)v[j] * sc_l[kb + j] + of_l[kb + j];
                    u = (u >= 0.f) ? u : alpha * u;
                    v[j] = (half_t)u;
                }
            }
            af[kk] = v;
        }

        for (int nt = 0; nt < NT; ++nt) {
            f4 acc = {0.f, 0.f, 0.f, 0.f};
#pragma unroll
            for (int kk = 0; kk < K / 32; ++kk) {
                h8 bf = *(const h8*)(wlds +
                                     ((size_t)(kk * 4 + kgrp) * CSTRIDE + nt * 16 + l16) * 8);
                acc = __builtin_amdgcn_mfma_f32_16x16x32_f16(af[kk], bf, acc, 0, 0, 0);
            }
            int col = colbase + nt * 16 + l16;
            if (col < Nc) {
#pragma unroll
                for (int j = 0; j < 4; ++j) {
                    int row = r0 + kgrp * 4 + j;
                    if (row < M) C[(size_t)row * Nc + col] = (half_t)acc[j];
                }
            }
        }
    }
}

// ---------------- BatchNorm stats (dedicated 512-block, LDS-reduced, atomics) ----------
// Round-14-proven: 512 blocks x ~2F atomics spread over distinct addresses is cheap.
// (Round 16's single-block statsred reducers were the regression: 1 CU reading 1MB.)

template <int F>
__global__ __launch_bounds__(256) void stats2_kernel(const half_t* __restrict__ z,
                                                     float* __restrict__ sums, int n) {
    constexpr int CB = F / 8;
    constexpr int RG = 256 / CB;
    __shared__ float red[256][16];
    int t = threadIdx.x;
    int cb = t % CB;
    int rg = t / CB;
    float sm[8], sq[8];
#pragma unroll
    for (int j = 0; j < 8; ++j) { sm[j] = 0.f; sq[j] = 0.f; }
    for (int r = blockIdx.x * RG + rg; r < n; r += gridDim.x * RG) {
        h8 v = *(const h8*)(z + (size_t)r * F + cb * 8);
#pragma unroll
        for (int j = 0; j < 8; ++j) {
            float f = (float)v[j];
            sm[j] += f;
            sq[j] = fmaf(f, f, sq[j]);
        }
    }
#pragma unroll
    for (int j = 0; j < 8; ++j) { red[t][j] = sm[j]; red[t][8 + j] = sq[j]; }
    __syncthreads();
    for (int o = t; o < 2 * F; o += 256) {
        int c = o % F, kind = o / F;
        int cbo = c >> 3, ci = (c & 7) + kind * 8;
        float v = 0.f;
#pragma unroll
        for (int g = 0; g < RG; ++g) v += red[g * CB + cbo][ci];
        atomicAdd(&sums[kind * 256 + c], v);
    }
}

// ---------------- launch ----------------

extern "C" void kernel_launch(void* const* d_in, const int* in_sizes, int n_in,
                              void* d_out, int out_size, void* d_ws, size_t ws_size,
                              hipStream_t stream) {
    const float* x   = (const float*)d_in[0];
    const int*   ei  = (const int*)d_in[1];
    const float* W1  = (const float*)d_in[2];
    const float* g1  = (const float*)d_in[4];
    const float* be1 = (const float*)d_in[5];
    const float* W2  = (const float*)d_in[6];
    const float* g2  = (const float*)d_in[8];
    const float* be2 = (const float*)d_in[9];
    const float* W3  = (const float*)d_in[10];
    const float* g3  = (const float*)d_in[12];
    const float* be3 = (const float*)d_in[13];
    const float* W4  = (const float*)d_in[14];
    const float* b4  = (const float*)d_in[15];
    const float* pa  = (const float*)d_in[16];
    // b1,b2,b3 dropped: constants before BatchNorm cancel exactly in mean subtraction.

    int N = in_sizes[0] / 128;
    int E = in_sizes[1] / 2;
    int B = (N + 255) >> 8;
    int chunk = (((E + 255) / 256) + 255) & ~255;
    int NB = (E + chunk - 1) / chunk;

    char* ws = (char*)d_ws;
    size_t off = 0;
    auto carve = [&](size_t bytes) -> char* {
        char* p = ws + off;
        off += (bytes + 255) & ~(size_t)255;
        return p;
    };
    float*          dinv      = (float*)carve((size_t)N * 4);
    int*            row_ptr   = (int*)carve((size_t)(N + 1) * 4);
    int*            hcnt      = (int*)carve((size_t)B * NB * 4);
    int*            btot      = (int*)carve((size_t)B * 4);
    int*            edge_base = (int*)carve((size_t)(B + 1) * 4);
    unsigned int*   ebuf      = (unsigned int*)carve((size_t)E * 4);
    unsigned short* colidx    = (unsigned short*)carve((size_t)(E + 16) * 2);
    float*          stats     = (float*)carve(3 * 512 * 4);
    half_t* W1t = (half_t*)carve((size_t)256 * 128 * 2);
    half_t* W2t = (half_t*)carve((size_t)128 * 256 * 2);
    half_t* W3t = (half_t*)carve((size_t)64 * 128 * 2);
    half_t* W4t = (half_t*)carve((size_t)64 * 64 * 2);
    half_t* hA  = (half_t*)carve((size_t)N * 256 * 2);  // Z1
    half_t* hB  = (half_t*)carve((size_t)N * 128 * 2);  // xh, P2
    half_t* hC  = (half_t*)carve((size_t)N * 128 * 2);  // P1, Z2
    half_t* hD1 = (half_t*)carve((size_t)N * 64 * 2);   // P3
    half_t* hD2 = (half_t*)carve((size_t)N * 64 * 2);   // Z3
    half_t* hE  = (half_t*)carve((size_t)N * 64 * 2);   // P4 padded
    (void)n_in; (void)out_size; (void)ws_size;

    // single memset covers colidx pad (from colidx+E) through stats (adjacent carves)
    {
        char* z0 = (char*)(colidx + E);
        char* z1 = (char*)stats + 3 * 512 * 4;
        hipMemsetAsync(z0, 0, (size_t)(z1 - z0), stream);
    }

    // CSR build
    csr_hist_kernel<<<NB, 256, 0, stream>>>(ei + E, hcnt, E, B, NB, chunk);
    csr_bscan_kernel<<<B, 256, 0, stream>>>(hcnt, btot, NB);
    csr_ebase_kernel<<<1, 256, 0, stream>>>(btot, edge_base, row_ptr, B, E, N);
    csr_part_kernel<<<NB, 256, 0, stream>>>(ei, hcnt, edge_base, ebuf, E, B, NB, chunk);
    csr_fill_kernel<<<B, 256, 0, stream>>>(ebuf, edge_base, row_ptr, dinv, colidx, N);

    wtall_kernel<<<(77824 + 255) / 256, 256, 0, stream>>>(W1, W2, W3, W4, W1t, W2t, W3t, W4t);

    int nTiles = (N + 63) / 64;
    int ab = (N + 3) / 4;

    // L1: x->fp16, aggregate, GEMM1 (col-split y=2, no stats), stats2<256> (atomics)
    f2h_kernel<<<(N * 128 / 4 + 255) / 256, 256, 0, stream>>>(x, hB, N * 128 / 4);
    aggh128_kernel<<<ab, 256, 0, stream>>>(hB, hC, row_ptr, colidx, dinv, N);
    mgemm_kernel<128, 8, false><<<dim3(512, 2), 256, 0, stream>>>(
        hC, W1t, nullptr, nullptr, nullptr, nullptr, hA, N, 256, nTiles);
    stats2_kernel<256><<<512, 256, 0, stream>>>(hA, stats, N);

    // L2: GEMM2 (BN1+PReLU coeffs in-kernel) -> P2, aggregate -> Z2, stats2
    mgemm_kernel<256, 4, true><<<dim3(512, 2), 256, 0, stream>>>(
        hA, W2t, stats, g1, be1, pa, hB, N, 128, nTiles);
    aggh128_kernel<<<ab, 256, 0, stream>>>(hB, hC, row_ptr, colidx, dinv, N);
    stats2_kernel<128><<<512, 256, 0, stream>>>(hC, stats + 512, N);

    // L3: GEMM3 (BN2 fused) -> P3, aggregate -> Z3, stats2
    mgemm_kernel<128, 4, true><<<nTiles, 256, 0, stream>>>(
        hC, W3t, stats + 512, g2, be2, pa, hD1, N, 64, nTiles);
    aggh64_kernel<<<ab, 256, 0, stream>>>(hD1, hD2, row_ptr, colidx, dinv, N);
    stats2_kernel<64><<<512, 256, 0, stream>>>(hD2, stats + 1024, N);

    // L4: GEMM4 (BN3 fused) -> P4 padded, aggregate + b4 + log_softmax -> out
    mgemm_kernel<64, 4, true><<<nTiles, 256, 0, stream>>>(
        hD2, W4t, stats + 1024, g3, be3, pa, hE, N, 64, nTiles);
    aggsm64_kernel<<<ab, 256, 0, stream>>>(hE, (float*)d_out, row_ptr, colidx, dinv, b4, N);
}

// Round 18
// 270.389 us; speedup vs baseline: 1.3293x; 1.0491x over previous
//
#include <hip/hip_runtime.h>
#include <cstdint>
#include <cmath>

typedef _Float16 half_t;
typedef _Float16 h2 __attribute__((ext_vector_type(2)));
typedef _Float16 h8 __attribute__((ext_vector_type(8)));
typedef float f4 __attribute__((ext_vector_type(4)));

// ================= CSR build: bucketed radix partition by dst>>8 =================

__global__ __launch_bounds__(256) void csr_hist_kernel(const int* __restrict__ ei_dst,
                                                       int* __restrict__ hcnt,
                                                       int E, int B, int NB, int chunk) {
    __shared__ int hist[256];
    int t = threadIdx.x;
    hist[t] = 0;
    __syncthreads();
    int base = blockIdx.x * chunk;
    int lim = min(base + chunk, E);
    for (int e = base + t; e < lim; e += 256) {
        int dst = ei_dst[e];
        atomicAdd(&hist[dst >> 8], 1);
    }
    __syncthreads();
    if (t < B) hcnt[t * NB + blockIdx.x] = hist[t];
}

__global__ __launch_bounds__(256) void csr_bscan_kernel(int* __restrict__ hcnt,
                                                        int* __restrict__ btot, int NB) {
    __shared__ int sh[256];
    int b = blockIdx.x, t = threadIdx.x;
    int v = (t < NB) ? hcnt[b * NB + t] : 0;
    sh[t] = v;
    __syncthreads();
    for (int off = 1; off < 256; off <<= 1) {
        int u = (t >= off) ? sh[t - off] : 0;
        __syncthreads();
        sh[t] += u;
        __syncthreads();
    }
    if (t < NB) hcnt[b * NB + t] = sh[t] - v;
    if (t == 255) btot[b] = sh[255];
}

__global__ __launch_bounds__(256) void csr_ebase_kernel(const int* __restrict__ btot,
                                                        int* __restrict__ edge_base,
                                                        int* __restrict__ row_ptr,
                                                        int B, int E, int n) {
    __shared__ int sh[256];
    int t = threadIdx.x;
    int v = (t < B) ? btot[t] : 0;
    sh[t] = v;
    __syncthreads();
    for (int off = 1; off < 256; off <<= 1) {
        int u = (t >= off) ? sh[t - off] : 0;
        __syncthreads();
        sh[t] += u;
        __syncthreads();
    }
    if (t < B) edge_base[t] = sh[t] - v;
    if (t == 0) {
        edge_base[B] = E;
        row_ptr[n] = E;
    }
}

__global__ __launch_bounds__(256) void csr_part_kernel(const int* __restrict__ ei,
                                                       const int* __restrict__ hcnt,
                                                       const int* __restrict__ edge_base,
                                                       unsigned int* __restrict__ ebuf,
                                                       int E, int B, int NB, int chunk) {
    __shared__ int lcur[256];
    int t = threadIdx.x;
    if (t < B) lcur[t] = edge_base[t] + hcnt[t * NB + blockIdx.x];
    __syncthreads();
    int base = blockIdx.x * chunk;
    int lim = min(base + chunk, E);
    for (int e = base + t; e < lim; e += 256) {
        int src = ei[e];
        int dst = ei[E + e];
        int b = dst >> 8;
        int pos = atomicAdd(&lcur[b], 1);
        ebuf[pos] = ((unsigned int)(dst & 255) << 16) | (unsigned int)src;
    }
}

__global__ __launch_bounds__(256) void csr_fill_kernel(const unsigned int* __restrict__ ebuf,
                                                       const int* __restrict__ edge_base,
                                                       int* __restrict__ row_ptr,
                                                       float* __restrict__ dinv,
                                                       unsigned short* __restrict__ colidx,
                                                       int n) {
    __shared__ int cnt[256];
    __shared__ int sc[256];
    __shared__ int cur[256];
    int b = blockIdx.x;
    int t = threadIdx.x;
    int seg_beg = edge_base[b];
    int seg_end = edge_base[b + 1];
    cnt[t] = 0;
    __syncthreads();
    for (int e = seg_beg + t; e < seg_end; e += 256)
        atomicAdd(&cnt[ebuf[e] >> 16], 1);
    __syncthreads();
    sc[t] = cnt[t];
    __syncthreads();
    for (int off = 1; off < 256; off <<= 1) {
        int u = (t >= off) ? sc[t - off] : 0;
        __syncthreads();
        sc[t] += u;
        __syncthreads();
    }
    int excl = seg_beg + sc[t] - cnt[t];
    int node = (b << 8) + t;
    if (node < n) {
        row_ptr[node] = excl;
        dinv[node] = rsqrtf((float)cnt[t] + 1.0f);
    }
    cur[t] = excl;
    __syncthreads();
    for (int e = seg_beg + t; e < seg_end; e += 256) {
        unsigned int p = ebuf[e];
        int pos = atomicAdd(&cur[p >> 16], 1);
        colidx[pos] = (unsigned short)(p & 0xffff);
    }
}

// ---------------- conversions ----------------

__global__ void f2h_kernel(const float* __restrict__ x, half_t* __restrict__ xh, int total4) {
    int i = blockIdx.x * blockDim.x + threadIdx.x;
    if (i < total4) {
        float4 v = *(const float4*)&x[i * 4];
        half_t* p = xh + (size_t)i * 4;
        p[0] = (half_t)v.x; p[1] = (half_t)v.y; p[2] = (half_t)v.z; p[3] = (half_t)v.w;
    }
}

// ---------------- weight transposes (one launch). Wt[n][k] = W[k][n] ----------------

__global__ __launch_bounds__(256) void wtall_kernel(const float* __restrict__ W1,
                                                    const float* __restrict__ W2,
                                                    const float* __restrict__ W3,
                                                    const float* __restrict__ W4,
                                                    half_t* __restrict__ W1t,
                                                    half_t* __restrict__ W2t,
                                                    half_t* __restrict__ W3t,
                                                    half_t* __restrict__ W4t) {
    int idx = blockIdx.x * blockDim.x + threadIdx.x;
    if (idx < 32768) {
        int n = idx >> 7, k = idx & 127;
        W1t[idx] = (half_t)W1[k * 256 + n];
    } else if (idx < 65536) {
        int r = idx - 32768;
        int n = r >> 8, k = r & 255;
        W2t[r] = (half_t)W2[k * 128 + n];
    } else if (idx < 73728) {
        int r = idx - 65536;
        int n = r >> 7, k = r & 127;
        W3t[r] = (half_t)W3[k * 64 + n];
    } else if (idx < 77824) {
        int r = idx - 73728;
        int n = r >> 6, k = r & 63;
        W4t[r] = (n < 40) ? (half_t)W4[k * 40 + n] : (half_t)0.f;
    }
}

// ------- aggregation (fp16): out[d] = dinv[d]*(sum dinv[s]*in[s] + dinv[d]*in[d]) --------
// Wave per node, 4 nodes/block, masked unroll-8 (colidx padded by 16 zeros).
// ALWAYS gather from fp16 (round 13). No fused stats in 12.5k-block grids (round 12, G12).

__global__ __launch_bounds__(256) void aggh128_kernel(const half_t* __restrict__ in,
                                                      half_t* __restrict__ out,
                                                      const int* __restrict__ row_ptr,
                                                      const unsigned short* __restrict__ colidx,
                                                      const float* __restrict__ dinv, int n) {
    int node = blockIdx.x * 4 + (threadIdx.x >> 6);
    if (node >= n) return;
    int c = threadIdx.x & 63;
    float dv = dinv[node];
    h2 self = *(const h2*)(in + (size_t)node * 128 + 2 * c);
    float acc0 = dv * (float)self[0], acc1 = dv * (float)self[1];
    int beg = row_ptr[node], end = row_ptr[node + 1];
    for (int k = beg; k < end; k += 8) {
        int idx[8]; float w[8]; h2 v[8];
#pragma unroll
        for (int j = 0; j < 8; ++j) idx[j] = colidx[k + j];
#pragma unroll
        for (int j = 0; j < 8; ++j) w[j] = (k + j < end) ? dinv[idx[j]] : 0.f;
#pragma unroll
        for (int j = 0; j < 8; ++j) v[j] = *(const h2*)(in + (size_t)idx[j] * 128 + 2 * c);
#pragma unroll
        for (int j = 0; j < 8; ++j) {
            acc0 = fmaf(w[j], (float)v[j][0], acc0);
            acc1 = fmaf(w[j], (float)v[j][1], acc1);
        }
    }
    h2 r;
    r[0] = (half_t)(dv * acc0);
    r[1] = (half_t)(dv * acc1);
    *(h2*)(out + (size_t)node * 128 + 2 * c) = r;
}

__global__ __launch_bounds__(256) void aggh64_kernel(const half_t* __restrict__ in,
                                                     half_t* __restrict__ out,
                                                     const int* __restrict__ row_ptr,
                                                     const unsigned short* __restrict__ colidx,
                                                     const float* __restrict__ dinv, int n) {
    int node = blockIdx.x * 4 + (threadIdx.x >> 6);
    if (node >= n) return;
    int c = threadIdx.x & 63;
    float dv = dinv[node];
    float acc = dv * (float)in[(size_t)node * 64 + c];
    int beg = row_ptr[node], end = row_ptr[node + 1];
    for (int k = beg; k < end; k += 8) {
        int idx[8]; float w[8]; float v[8];
#pragma unroll
        for (int j = 0; j < 8; ++j) idx[j] = colidx[k + j];
#pragma unroll
        for (int j = 0; j < 8; ++j) w[j] = (k + j < end) ? dinv[idx[j]] : 0.f;
#pragma unroll
        for (int j = 0; j < 8; ++j) v[j] = (float)in[(size_t)idx[j] * 64 + c];
#pragma unroll
        for (int j = 0; j < 8; ++j) acc = fmaf(w[j], v[j], acc);
    }
    out[(size_t)node * 64 + c] = (half_t)(dv * acc);
}

// final layer v2: one node per 32-lane HALF-WAVE (8 nodes/block) — no mirrored lanes.
// P4 padded [N,64] (row = one 128B line, covered by 32 lanes x h2); shuffle width 32.
__global__ __launch_bounds__(256) void aggsm64_kernel(const half_t* __restrict__ in,
                                                      float* __restrict__ out,
                                                      const int* __restrict__ row_ptr,
                                                      const unsigned short* __restrict__ colidx,
                                                      const float* __restrict__ dinv,
                                                      const float* __restrict__ b4, int n) {
    int node = blockIdx.x * 8 + (threadIdx.x >> 5);
    if (node >= n) return;
    int c = threadIdx.x & 31;
    float dv = dinv[node];
    h2 self = *(const h2*)(in + (size_t)node * 64 + 2 * c);
    float acc0 = dv * (float)self[0], acc1 = dv * (float)self[1];
    int beg = row_ptr[node], end = row_ptr[node + 1];
    for (int k = beg; k < end; k += 8) {
        int idx[8]; float w[8]; h2 v[8];
#pragma unroll
        for (int j = 0; j < 8; ++j) idx[j] = colidx[k + j];
#pragma unroll
        for (int j = 0; j < 8; ++j) w[j] = (k + j < end) ? dinv[idx[j]] : 0.f;
#pragma unroll
        for (int j = 0; j < 8; ++j) v[j] = *(const h2*)(in + (size_t)idx[j] * 64 + 2 * c);
#pragma unroll
        for (int j = 0; j < 8; ++j) {
            acc0 = fmaf(w[j], (float)v[j][0], acc0);
            acc1 = fmaf(w[j], (float)v[j][1], acc1);
        }
    }
    int col0 = 2 * c, col1 = 2 * c + 1;
    float z0 = (col0 < 40) ? (dv * acc0 + b4[col0]) : -INFINITY;
    float z1 = (col1 < 40) ? (dv * acc1 + b4[col1]) : -INFINITY;
    float m = fmaxf(z0, z1);
#pragma unroll
    for (int off = 16; off > 0; off >>= 1) m = fmaxf(m, __shfl_xor(m, off, 32));
    float e0 = (col0 < 40) ? expf(z0 - m) : 0.f;
    float e1 = (col1 < 40) ? expf(z1 - m) : 0.f;
    float s = e0 + e1;
#pragma unroll
    for (int off = 16; off > 0; off >>= 1) s += __shfl_xor(s, off, 32);
    float ls = logf(s);
    if (c < 20) {
        float2 r = make_float2(z0 - m - ls, z1 - m - ls);
        *(float2*)(out + (size_t)node * 40 + 2 * c) = r;
    }
}

// ---------------- MFMA GEMM v5: col-split LDS weights + bank-pad + BNC (no stats) -------

template <int K, int NT, bool BNC>
__global__ __launch_bounds__(256) void mgemm_kernel(const half_t* __restrict__ A,
                                                    const half_t* __restrict__ Wt,  // [cols][K]
                                                    const float* __restrict__ bn_stats,
                                                    const float* __restrict__ g,
                                                    const float* __restrict__ be,
                                                    const float* __restrict__ pa,
                                                    half_t* __restrict__ C,
                                                    int M, int Nc, int nTiles) {
    constexpr int NR = NT * 16;
    constexpr int CH = K / 8;
    constexpr int LOG_CH = (CH == 8) ? 3 : (CH == 16 ? 4 : 5);
    constexpr int CSTRIDE = NR + 1;  // +16B bank pad
    __shared__ half_t wlds[CH * CSTRIDE * 8];
    __shared__ float sc_l[K], of_l[K];

    int t = threadIdx.x;
    int colbase = blockIdx.y * NR;
    for (int idx = t; idx < NR * CH; idx += 256) {
        int row = idx >> LOG_CH;
        int c = idx & (CH - 1);
        *(h8*)(wlds + ((size_t)c * CSTRIDE + row) * 8) =
            *(const h8*)(Wt + (size_t)(colbase + row) * K + c * 8);
    }
    if (BNC && t < K) {
        float inv_n = 1.0f / (float)M;
        float mean = bn_stats[t] * inv_n;
        float var = bn_stats[256 + t] * inv_n - mean * mean;
        float rstd = rsqrtf(var + 1e-5f);
        float s = g[t] * rstd;
        sc_l[t] = s;
        of_l[t] = be[t] - mean * s;
    }
    int wave = t >> 6;
    int lane = t & 63;
    int l16 = lane & 15, kgrp = lane >> 4;
    float alpha = BNC ? pa[0] : 0.f;
    __syncthreads();

    for (int tile = blockIdx.x; tile < nTiles; tile += gridDim.x) {
        int r0 = tile * 64 + wave * 16;
        int arow = r0 + l16;
        bool rowok = (arow < M);
        const half_t* Ap = A + (size_t)arow * K + kgrp * 8;
        h8 af[K / 32];
#pragma unroll
        for (int kk = 0; kk < K / 32; ++kk) {
            h8 v;
            if (rowok) {
                v = *(const h8*)(Ap + kk * 32);
            } else {
#pragma unroll
                for (int j = 0; j < 8; ++j) v[j] = (half_t)0.f;
            }
            if (BNC) {
                int kb = kk * 32 + kgrp * 8;
#pragma unroll
                for (int j = 0; j < 8; ++j) {
                    float u = (float)v[j] * sc_l[kb + j] + of_l[kb + j];
                    u = (u >= 0.f) ? u : alpha * u;
                    v[j] = (half_t)u;
                }
            }
            af[kk] = v;
        }

        for (int nt = 0; nt < NT; ++nt) {
            f4 acc = {0.f, 0.f, 0.f, 0.f};
#pragma unroll
            for (int kk = 0; kk < K / 32; ++kk) {
                h8 bf = *(const h8*)(wlds +
                                     ((size_t)(kk * 4 + kgrp) * CSTRIDE + nt * 16 + l16) * 8);
                acc = __builtin_amdgcn_mfma_f32_16x16x32_f16(af[kk], bf, acc, 0, 0, 0);
            }
            int col = colbase + nt * 16 + l16;
            if (col < Nc) {
#pragma unroll
                for (int j = 0; j < 4; ++j) {
                    int row = r0 + kgrp * 4 + j;
                    if (row < M) C[(size_t)row * Nc + col] = (half_t)acc[j];
                }
            }
        }
    }
}

// ---------------- BatchNorm stats (dedicated 512-block, LDS-reduced, atomics) ----------

template <int F>
__global__ __launch_bounds__(256) void stats2_kernel(const half_t* __restrict__ z,
                                                     float* __restrict__ sums, int n) {
    constexpr int CB = F / 8;
    constexpr int RG = 256 / CB;
    __shared__ float red[256][16];
    int t = threadIdx.x;
    int cb = t % CB;
    int rg = t / CB;
    float sm[8], sq[8];
#pragma unroll
    for (int j = 0; j < 8; ++j) { sm[j] = 0.f; sq[j] = 0.f; }
    for (int r = blockIdx.x * RG + rg; r < n; r += gridDim.x * RG) {
        h8 v = *(const h8*)(z + (size_t)r * F + cb * 8);
#pragma unroll
        for (int j = 0; j < 8; ++j) {
            float f = (float)v[j];
            sm[j] += f;
            sq[j] = fmaf(f, f, sq[j]);
        }
    }
#pragma unroll
    for (int j = 0; j < 8; ++j) { red[t][j] = sm[j]; red[t][8 + j] = sq[j]; }
    __syncthreads();
    for (int o = t; o < 2 * F; o += 256) {
        int c = o % F, kind = o / F;
        int cbo = c >> 3, ci = (c & 7) + kind * 8;
        float v = 0.f;
#pragma unroll
        for (int g = 0; g < RG; ++g) v += red[g * CB + cbo][ci];
        atomicAdd(&sums[kind * 256 + c], v);
    }
}

// ---------------- launch ----------------

extern "C" void kernel_launch(void* const* d_in, const int* in_sizes, int n_in,
                              void* d_out, int out_size, void* d_ws, size_t ws_size,
                              hipStream_t stream) {
    const float* x   = (const float*)d_in[0];
    const int*   ei  = (const int*)d_in[1];
    const float* W1  = (const float*)d_in[2];
    const float* g1  = (const float*)d_in[4];
    const float* be1 = (const float*)d_in[5];
    const float* W2  = (const float*)d_in[6];
    const float* g2  = (const float*)d_in[8];
    const float* be2 = (const float*)d_in[9];
    const float* W3  = (const float*)d_in[10];
    const float* g3  = (const float*)d_in[12];
    const float* be3 = (const float*)d_in[13];
    const float* W4  = (const float*)d_in[14];
    const float* b4  = (const float*)d_in[15];
    const float* pa  = (const float*)d_in[16];
    // b1,b2,b3 dropped: constants before BatchNorm cancel exactly in mean subtraction.

    int N = in_sizes[0] / 128;
    int E = in_sizes[1] / 2;
    int B = (N + 255) >> 8;
    int chunk = (((E + 255) / 256) + 255) & ~255;
    int NB = (E + chunk - 1) / chunk;

    char* ws = (char*)d_ws;
    size_t off = 0;
    auto carve = [&](size_t bytes) -> char* {
        char* p = ws + off;
        off += (bytes + 255) & ~(size_t)255;
        return p;
    };
    float*          dinv      = (float*)carve((size_t)N * 4);
    int*            row_ptr   = (int*)carve((size_t)(N + 1) * 4);
    int*            hcnt      = (int*)carve((size_t)B * NB * 4);
    int*            btot      = (int*)carve((size_t)B * 4);
    int*            edge_base = (int*)carve((size_t)(B + 1) * 4);
    unsigned int*   ebuf      = (unsigned int*)carve((size_t)E * 4);
    unsigned short* colidx    = (unsigned short*)carve((size_t)(E + 16) * 2);
    float*          stats     = (float*)carve(3 * 512 * 4);
    half_t* W1t = (half_t*)carve((size_t)256 * 128 * 2);
    half_t* W2t = (half_t*)carve((size_t)128 * 256 * 2);
    half_t* W3t = (half_t*)carve((size_t)64 * 128 * 2);
    half_t* W4t = (half_t*)carve((size_t)64 * 64 * 2);
    half_t* hA  = (half_t*)carve((size_t)N * 256 * 2);  // Z1
    half_t* hB  = (half_t*)carve((size_t)N * 128 * 2);  // xh, P2
    half_t* hC  = (half_t*)carve((size_t)N * 128 * 2);  // P1, Z2
    half_t* hD1 = (half_t*)carve((size_t)N * 64 * 2);   // P3
    half_t* hD2 = (half_t*)carve((size_t)N * 64 * 2);   // Z3
    half_t* hE  = (half_t*)carve((size_t)N * 64 * 2);   // P4 padded
    (void)n_in; (void)out_size; (void)ws_size;

    // single memset covers colidx pad (from colidx+E) through stats (adjacent carves)
    {
        char* z0 = (char*)(colidx + E);
        char* z1 = (char*)stats + 3 * 512 * 4;
        hipMemsetAsync(z0, 0, (size_t)(z1 - z0), stream);
    }

    // CSR build
    csr_hist_kernel<<<NB, 256, 0, stream>>>(ei + E, hcnt, E, B, NB, chunk);
    csr_bscan_kernel<<<B, 256, 0, stream>>>(hcnt, btot, NB);
    csr_ebase_kernel<<<1, 256, 0, stream>>>(btot, edge_base, row_ptr, B, E, N);
    csr_part_kernel<<<NB, 256, 0, stream>>>(ei, hcnt, edge_base, ebuf, E, B, NB, chunk);
    csr_fill_kernel<<<B, 256, 0, stream>>>(ebuf, edge_base, row_ptr, dinv, colidx, N);

    wtall_kernel<<<(77824 + 255) / 256, 256, 0, stream>>>(W1, W2, W3, W4, W1t, W2t, W3t, W4t);

    int nTiles = (N + 63) / 64;
    int ab = (N + 3) / 4;

    // L1: x->fp16, aggregate, GEMM1 (col-split y=2), stats2<256>
    f2h_kernel<<<(N * 128 / 4 + 255) / 256, 256, 0, stream>>>(x, hB, N * 128 / 4);
    aggh128_kernel<<<ab, 256, 0, stream>>>(hB, hC, row_ptr, colidx, dinv, N);
    mgemm_kernel<128, 8, false><<<dim3(512, 2), 256, 0, stream>>>(
        hC, W1t, nullptr, nullptr, nullptr, nullptr, hA, N, 256, nTiles);
    stats2_kernel<256><<<512, 256, 0, stream>>>(hA, stats, N);

    // L2: GEMM2 (BN1+PReLU coeffs in-kernel) -> P2, aggregate -> Z2, stats2
    mgemm_kernel<256, 4, true><<<dim3(512, 2), 256, 0, stream>>>(
        hA, W2t, stats, g1, be1, pa, hB, N, 128, nTiles);
    aggh128_kernel<<<ab, 256, 0, stream>>>(hB, hC, row_ptr, colidx, dinv, N);
    stats2_kernel<128><<<512, 256, 0, stream>>>(hC, stats + 512, N);

    // L3: GEMM3 (BN2 fused) -> P3, aggregate -> Z3, stats2
    mgemm_kernel<128, 4, true><<<nTiles, 256, 0, stream>>>(
        hC, W3t, stats + 512, g2, be2, pa, hD1, N, 64, nTiles);
    aggh64_kernel<<<ab, 256, 0, stream>>>(hD1, hD2, row_ptr, colidx, dinv, N);
    stats2_kernel<64><<<512, 256, 0, stream>>>(hD2, stats + 1024, N);

    // L4: GEMM4 (BN3 fused) -> P4 padded, aggregate + b4 + log_softmax -> out
    mgemm_kernel<64, 4, true><<<nTiles, 256, 0, stream>>>(
        hD2, W4t, stats + 1024, g3, be3, pa, hE, N, 64, nTiles);
    aggsm64_kernel<<<(N + 7) / 8, 256, 0, stream>>>(hE, (float*)d_out, row_ptr, colidx,
                                                    dinv, b4, N);
}

// Round 19
// 257.958 us; speedup vs baseline: 1.3934x; 1.0482x over previous
//
#include <hip/hip_runtime.h>
#include <cstdint>
#include <cmath>

typedef _Float16 half_t;
typedef _Float16 h2 __attribute__((ext_vector_type(2)));
typedef _Float16 h8 __attribute__((ext_vector_type(8)));
typedef float f4 __attribute__((ext_vector_type(4)));

// ================= CSR build: bucketed radix partition by dst>>8 =================

__global__ __launch_bounds__(256) void csr_hist_kernel(const int* __restrict__ ei_dst,
                                                       int* __restrict__ hcnt,
                                                       int E, int B, int NB, int chunk) {
    __shared__ int hist[256];
    int t = threadIdx.x;
    hist[t] = 0;
    __syncthreads();
    int base = blockIdx.x * chunk;
    int lim = min(base + chunk, E);
    for (int e = base + t; e < lim; e += 256) {
        int dst = ei_dst[e];
        atomicAdd(&hist[dst >> 8], 1);
    }
    __syncthreads();
    if (t < B) hcnt[t * NB + blockIdx.x] = hist[t];
}

__global__ __launch_bounds__(256) void csr_bscan_kernel(int* __restrict__ hcnt,
                                                        int* __restrict__ btot, int NB) {
    __shared__ int sh[256];
    int b = blockIdx.x, t = threadIdx.x;
    int v = (t < NB) ? hcnt[b * NB + t] : 0;
    sh[t] = v;
    __syncthreads();
    for (int off = 1; off < 256; off <<= 1) {
        int u = (t >= off) ? sh[t - off] : 0;
        __syncthreads();
        sh[t] += u;
        __syncthreads();
    }
    if (t < NB) hcnt[b * NB + t] = sh[t] - v;
    if (t == 255) btot[b] = sh[255];
}

__global__ __launch_bounds__(256) void csr_ebase_kernel(const int* __restrict__ btot,
                                                        int* __restrict__ edge_base,
                                                        int* __restrict__ row_ptr,
                                                        int B, int E, int n) {
    __shared__ int sh[256];
    int t = threadIdx.x;
    int v = (t < B) ? btot[t] : 0;
    sh[t] = v;
    __syncthreads();
    for (int off = 1; off < 256; off <<= 1) {
        int u = (t >= off) ? sh[t - off] : 0;
        __syncthreads();
        sh[t] += u;
        __syncthreads();
    }
    if (t < B) edge_base[t] = sh[t] - v;
    if (t == 0) {
        edge_base[B] = E;
        row_ptr[n] = E;
    }
}

__global__ __launch_bounds__(256) void csr_part_kernel(const int* __restrict__ ei,
                                                       const int* __restrict__ hcnt,
                                                       const int* __restrict__ edge_base,
                                                       unsigned int* __restrict__ ebuf,
                                                       int E, int B, int NB, int chunk) {
    __shared__ int lcur[256];
    int t = threadIdx.x;
    if (t < B) lcur[t] = edge_base[t] + hcnt[t * NB + blockIdx.x];
    __syncthreads();
    int base = blockIdx.x * chunk;
    int lim = min(base + chunk, E);
    for (int e = base + t; e < lim; e += 256) {
        int src = ei[e];
        int dst = ei[E + e];
        int b = dst >> 8;
        int pos = atomicAdd(&lcur[b], 1);
        ebuf[pos] = ((unsigned int)(dst & 255) << 16) | (unsigned int)src;
    }
}

__global__ __launch_bounds__(256) void csr_fill_kernel(const unsigned int* __restrict__ ebuf,
                                                       const int* __restrict__ edge_base,
                                                       int* __restrict__ row_ptr,
                                                       float* __restrict__ dinv,
                                                       unsigned short* __restrict__ colidx,
                                                       int n) {
    __shared__ int cnt[256];
    __shared__ int sc[256];
    __shared__ int cur[256];
    int b = blockIdx.x;
    int t = threadIdx.x;
    int seg_beg = edge_base[b];
    int seg_end = edge_base[b + 1];
    cnt[t] = 0;
    __syncthreads();
    for (int e = seg_beg + t; e < seg_end; e += 256)
        atomicAdd(&cnt[ebuf[e] >> 16], 1);
    __syncthreads();
    sc[t] = cnt[t];
    __syncthreads();
    for (int off = 1; off < 256; off <<= 1) {
        int u = (t >= off) ? sc[t - off] : 0;
        __syncthreads();
        sc[t] += u;
        __syncthreads();
    }
    int excl = seg_beg + sc[t] - cnt[t];
    int node = (b << 8) + t;
    if (node < n) {
        row_ptr[node] = excl;
        dinv[node] = rsqrtf((float)cnt[t] + 1.0f);
    }
    cur[t] = excl;
    __syncthreads();
    for (int e = seg_beg + t; e < seg_end; e += 256) {
        unsigned int p = ebuf[e];
        int pos = atomicAdd(&cur[p >> 16], 1);
        colidx[pos] = (unsigned short)(p & 0xffff);
    }
}

// ---- prep: weight transposes (blocks 0..303) + x->fp16 (remaining blocks), one launch ----

#define WT_BLOCKS 304  // ceil(77824/256)

__global__ __launch_bounds__(256) void prep_kernel(const float* __restrict__ W1,
                                                   const float* __restrict__ W2,
                                                   const float* __restrict__ W3,
                                                   const float* __restrict__ W4,
                                                   half_t* __restrict__ W1t,
                                                   half_t* __restrict__ W2t,
                                                   half_t* __restrict__ W3t,
                                                   half_t* __restrict__ W4t,
                                                   const float* __restrict__ x,
                                                   half_t* __restrict__ xh, int total4) {
    if (blockIdx.x < WT_BLOCKS) {
        int idx = blockIdx.x * 256 + threadIdx.x;
        if (idx < 32768) {
            int n = idx >> 7, k = idx & 127;
            W1t[idx] = (half_t)W1[k * 256 + n];
        } else if (idx < 65536) {
            int r = idx - 32768;
            int n = r >> 8, k = r & 255;
            W2t[r] = (half_t)W2[k * 128 + n];
        } else if (idx < 73728) {
            int r = idx - 65536;
            int n = r >> 7, k = r & 127;
            W3t[r] = (half_t)W3[k * 64 + n];
        } else if (idx < 77824) {
            int r = idx - 73728;
            int n = r >> 6, k = r & 63;
            W4t[r] = (n < 40) ? (half_t)W4[k * 40 + n] : (half_t)0.f;
        }
    } else {
        int i = (blockIdx.x - WT_BLOCKS) * 256 + threadIdx.x;
        if (i < total4) {
            float4 v = *(const float4*)&x[i * 4];
            half_t* p = xh + (size_t)i * 4;
            p[0] = (half_t)v.x; p[1] = (half_t)v.y; p[2] = (half_t)v.z; p[3] = (half_t)v.w;
        }
    }
}

// ------- aggregation (fp16): out[d] = dinv[d]*(sum dinv[s]*in[s] + dinv[d]*in[d]) --------
// Masked unroll-8 (colidx padded by 16 zeros); gather from fp16 only (round 13);
// no fused stats in big grids (round 12, G12).

// F=128: one 64-lane wave per node (row 256B), 4 nodes/block.
__global__ __launch_bounds__(256) void aggh128_kernel(const half_t* __restrict__ in,
                                                      half_t* __restrict__ out,
                                                      const int* __restrict__ row_ptr,
                                                      const unsigned short* __restrict__ colidx,
                                                      const float* __restrict__ dinv, int n) {
    int node = blockIdx.x * 4 + (threadIdx.x >> 6);
    if (node >= n) return;
    int c = threadIdx.x & 63;
    float dv = dinv[node];
    h2 self = *(const h2*)(in + (size_t)node * 128 + 2 * c);
    float acc0 = dv * (float)self[0], acc1 = dv * (float)self[1];
    int beg = row_ptr[node], end = row_ptr[node + 1];
    for (int k = beg; k < end; k += 8) {
        int idx[8]; float w[8]; h2 v[8];
#pragma unroll
        for (int j = 0; j < 8; ++j) idx[j] = colidx[k + j];
#pragma unroll
        for (int j = 0; j < 8; ++j) w[j] = (k + j < end) ? dinv[idx[j]] : 0.f;
#pragma unroll
        for (int j = 0; j < 8; ++j) v[j] = *(const h2*)(in + (size_t)idx[j] * 128 + 2 * c);
#pragma unroll
        for (int j = 0; j < 8; ++j) {
            acc0 = fmaf(w[j], (float)v[j][0], acc0);
            acc1 = fmaf(w[j], (float)v[j][1], acc1);
        }
    }
    h2 r;
    r[0] = (half_t)(dv * acc0);
    r[1] = (half_t)(dv * acc1);
    *(h2*)(out + (size_t)node * 128 + 2 * c) = r;
}

// F=64: one node per 32-lane half-wave (row = 128B line), 8 nodes/block, h2 loads.
__global__ __launch_bounds__(256) void aggh64_kernel(const half_t* __restrict__ in,
                                                     half_t* __restrict__ out,
                                                     const int* __restrict__ row_ptr,
                                                     const unsigned short* __restrict__ colidx,
                                                     const float* __restrict__ dinv, int n) {
    int node = blockIdx.x * 8 + (threadIdx.x >> 5);
    if (node >= n) return;
    int c = threadIdx.x & 31;
    float dv = dinv[node];
    h2 self = *(const h2*)(in + (size_t)node * 64 + 2 * c);
    float acc0 = dv * (float)self[0], acc1 = dv * (float)self[1];
    int beg = row_ptr[node], end = row_ptr[node + 1];
    for (int k = beg; k < end; k += 8) {
        int idx[8]; float w[8]; h2 v[8];
#pragma unroll
        for (int j = 0; j < 8; ++j) idx[j] = colidx[k + j];
#pragma unroll
        for (int j = 0; j < 8; ++j) w[j] = (k + j < end) ? dinv[idx[j]] : 0.f;
#pragma unroll
        for (int j = 0; j < 8; ++j) v[j] = *(const h2*)(in + (size_t)idx[j] * 64 + 2 * c);
#pragma unroll
        for (int j = 0; j < 8; ++j) {
            acc0 = fmaf(w[j], (float)v[j][0], acc0);
            acc1 = fmaf(w[j], (float)v[j][1], acc1);
        }
    }
    h2 r;
    r[0] = (half_t)(dv * acc0);
    r[1] = (half_t)(dv * acc1);
    *(h2*)(out + (size_t)node * 64 + 2 * c) = r;
}

// final layer: one node per 32-lane half-wave, aggregate + b4 + log_softmax -> f32 out
__global__ __launch_bounds__(256) void aggsm64_kernel(const half_t* __restrict__ in,
                                                      float* __restrict__ out,
                                                      const int* __restrict__ row_ptr,
                                                      const unsigned short* __restrict__ colidx,
                                                      const float* __restrict__ dinv,
                                                      const float* __restrict__ b4, int n) {
    int node = blockIdx.x * 8 + (threadIdx.x >> 5);
    if (node >= n) return;
    int c = threadIdx.x & 31;
    float dv = dinv[node];
    h2 self = *(const h2*)(in + (size_t)node * 64 + 2 * c);
    float acc0 = dv * (float)self[0], acc1 = dv * (float)self[1];
    int beg = row_ptr[node], end = row_ptr[node + 1];
    for (int k = beg; k < end; k += 8) {
        int idx[8]; float w[8]; h2 v[8];
#pragma unroll
        for (int j = 0; j < 8; ++j) idx[j] = colidx[k + j];
#pragma unroll
        for (int j = 0; j < 8; ++j) w[j] = (k + j < end) ? dinv[idx[j]] : 0.f;
#pragma unroll
        for (int j = 0; j < 8; ++j) v[j] = *(const h2*)(in + (size_t)idx[j] * 64 + 2 * c);
#pragma unroll
        for (int j = 0; j < 8; ++j) {
            acc0 = fmaf(w[j], (float)v[j][0], acc0);
            acc1 = fmaf(w[j], (float)v[j][1], acc1);
        }
    }
    int col0 = 2 * c, col1 = 2 * c + 1;
    float z0 = (col0 < 40) ? (dv * acc0 + b4[col0]) : -INFINITY;
    float z1 = (col1 < 40) ? (dv * acc1 + b4[col1]) : -INFINITY;
    float m = fmaxf(z0, z1);
#pragma unroll
    for (int off = 16; off > 0; off >>= 1) m = fmaxf(m, __shfl_xor(m, off, 32));
    float e0 = (col0 < 40) ? expf(z0 - m) : 0.f;
    float e1 = (col1 < 40) ? expf(z1 - m) : 0.f;
    float s = e0 + e1;
#pragma unroll
    for (int off = 16; off > 0; off >>= 1) s += __shfl_xor(s, off, 32);
    float ls = logf(s);
    if (c < 20) {
        float2 r = make_float2(z0 - m - ls, z1 - m - ls);
        *(float2*)(out + (size_t)node * 40 + 2 * c) = r;
    }
}

// ---------------- MFMA GEMM v5: col-split LDS weights + bank-pad + BNC (no stats) -------

template <int K, int NT, bool BNC>
__global__ __launch_bounds__(256) void mgemm_kernel(const half_t* __restrict__ A,
                                                    const half_t* __restrict__ Wt,  // [cols][K]
                                                    const float* __restrict__ bn_stats,
                                                    const float* __restrict__ g,
                                                    const float* __restrict__ be,
                                                    const float* __restrict__ pa,
                                                    half_t* __restrict__ C,
                                                    int M, int Nc, int nTiles) {
    constexpr int NR = NT * 16;
    constexpr int CH = K / 8;
    constexpr int LOG_CH = (CH == 8) ? 3 : (CH == 16 ? 4 : 5);
    constexpr int CSTRIDE = NR + 1;  // +16B bank pad
    __shared__ half_t wlds[CH * CSTRIDE * 8];
    __shared__ float sc_l[K], of_l[K];

    int t = threadIdx.x;
    int colbase = blockIdx.y * NR;
    for (int idx = t; idx < NR * CH; idx += 256) {
        int row = idx >> LOG_CH;
        int c = idx & (CH - 1);
        *(h8*)(wlds + ((size_t)c * CSTRIDE + row) * 8) =
            *(const h8*)(Wt + (size_t)(colbase + row) * K + c * 8);
    }
    if (BNC && t < K) {
        float inv_n = 1.0f / (float)M;
        float mean = bn_stats[t] * inv_n;
        float var = bn_stats[256 + t] * inv_n - mean * mean;
        float rstd = rsqrtf(var + 1e-5f);
        float s = g[t] * rstd;
        sc_l[t] = s;
        of_l[t] = be[t] - mean * s;
    }
    int wave = t >> 6;
    int lane = t & 63;
    int l16 = lane & 15, kgrp = lane >> 4;
    float alpha = BNC ? pa[0] : 0.f;
    __syncthreads();

    for (int tile = blockIdx.x; tile < nTiles; tile += gridDim.x) {
        int r0 = tile * 64 + wave * 16;
        int arow = r0 + l16;
        bool rowok = (arow < M);
        const half_t* Ap = A + (size_t)arow * K + kgrp * 8;
        h8 af[K / 32];
#pragma unroll
        for (int kk = 0; kk < K / 32; ++kk) {
            h8 v;
            if (rowok) {
                v = *(const h8*)(Ap + kk * 32);
            } else {
#pragma unroll
                for (int j = 0; j < 8; ++j) v[j] = (half_t)0.f;
            }
            if (BNC) {
                int kb = kk * 32 + kgrp * 8;
#pragma unroll
                for (int j = 0; j < 8; ++j) {
                    float u = (float)v[j] * sc_l[kb + j] + of_l[kb + j];
                    u = (u >= 0.f) ? u : alpha * u;
                    v[j] = (half_t)u;
                }
            }
            af[kk] = v;
        }

        for (int nt = 0; nt < NT; ++nt) {
            f4 acc = {0.f, 0.f, 0.f, 0.f};
#pragma unroll
            for (int kk = 0; kk < K / 32; ++kk) {
                h8 bf = *(const h8*)(wlds +
                                     ((size_t)(kk * 4 + kgrp) * CSTRIDE + nt * 16 + l16) * 8);
                acc = __builtin_amdgcn_mfma_f32_16x16x32_f16(af[kk], bf, acc, 0, 0, 0);
            }
            int col = colbase + nt * 16 + l16;
            if (col < Nc) {
#pragma unroll
                for (int j = 0; j < 4; ++j) {
                    int row = r0 + kgrp * 4 + j;
                    if (row < M) C[(size_t)row * Nc + col] = (half_t)acc[j];
                }
            }
        }
    }
}

// ---------------- BatchNorm stats (dedicated 512-block, LDS-reduced, atomics) ----------

template <int F>
__global__ __launch_bounds__(256) void stats2_kernel(const half_t* __restrict__ z,
                                                     float* __restrict__ sums, int n) {
    constexpr int CB = F / 8;
    constexpr int RG = 256 / CB;
    __shared__ float red[256][16];
    int t = threadIdx.x;
    int cb = t % CB;
    int rg = t / CB;
    float sm[8], sq[8];
#pragma unroll
    for (int j = 0; j < 8; ++j) { sm[j] = 0.f; sq[j] = 0.f; }
    for (int r = blockIdx.x * RG + rg; r < n; r += gridDim.x * RG) {
        h8 v = *(const h8*)(z + (size_t)r * F + cb * 8);
#pragma unroll
        for (int j = 0; j < 8; ++j) {
            float f = (float)v[j];
            sm[j] += f;
            sq[j] = fmaf(f, f, sq[j]);
        }
    }
#pragma unroll
    for (int j = 0; j < 8; ++j) { red[t][j] = sm[j]; red[t][8 + j] = sq[j]; }
    __syncthreads();
    for (int o = t; o < 2 * F; o += 256) {
        int c = o % F, kind = o / F;
        int cbo = c >> 3, ci = (c & 7) + kind * 8;
        float v = 0.f;
#pragma unroll
        for (int g = 0; g < RG; ++g) v += red[g * CB + cbo][ci];
        atomicAdd(&sums[kind * 256 + c], v);
    }
}

// ---------------- launch ----------------

extern "C" void kernel_launch(void* const* d_in, const int* in_sizes, int n_in,
                              void* d_out, int out_size, void* d_ws, size_t ws_size,
                              hipStream_t stream) {
    const float* x   = (const float*)d_in[0];
    const int*   ei  = (const int*)d_in[1];
    const float* W1  = (const float*)d_in[2];
    const float* g1  = (const float*)d_in[4];
    const float* be1 = (const float*)d_in[5];
    const float* W2  = (const float*)d_in[6];
    const float* g2  = (const float*)d_in[8];
    const float* be2 = (const float*)d_in[9];
    const float* W3  = (const float*)d_in[10];
    const float* g3  = (const float*)d_in[12];
    const float* be3 = (const float*)d_in[13];
    const float* W4  = (const float*)d_in[14];
    const float* b4  = (const float*)d_in[15];
    const float* pa  = (const float*)d_in[16];
    // b1,b2,b3 dropped: constants before BatchNorm cancel exactly in mean subtraction.

    int N = in_sizes[0] / 128;
    int E = in_sizes[1] / 2;
    int B = (N + 255) >> 8;
    int chunk = (((E + 255) / 256) + 255) & ~255;
    int NB = (E + chunk - 1) / chunk;

    char* ws = (char*)d_ws;
    size_t off = 0;
    auto carve = [&](size_t bytes) -> char* {
        char* p = ws + off;
        off += (bytes + 255) & ~(size_t)255;
        return p;
    };
    float*          dinv      = (float*)carve((size_t)N * 4);
    int*            row_ptr   = (int*)carve((size_t)(N + 1) * 4);
    int*            hcnt      = (int*)carve((size_t)B * NB * 4);
    int*            btot      = (int*)carve((size_t)B * 4);
    int*            edge_base = (int*)carve((size_t)(B + 1) * 4);
    unsigned int*   ebuf      = (unsigned int*)carve((size_t)E * 4);
    unsigned short* colidx    = (unsigned short*)carve((size_t)(E + 16) * 2);
    float*          stats     = (float*)carve(3 * 512 * 4);
    half_t* W1t = (half_t*)carve((size_t)256 * 128 * 2);
    half_t* W2t = (half_t*)carve((size_t)128 * 256 * 2);
    half_t* W3t = (half_t*)carve((size_t)64 * 128 * 2);
    half_t* W4t = (half_t*)carve((size_t)64 * 64 * 2);
    half_t* hA  = (half_t*)carve((size_t)N * 256 * 2);  // Z1
    half_t* hB  = (half_t*)carve((size_t)N * 128 * 2);  // xh, P2
    half_t* hC  = (half_t*)carve((size_t)N * 128 * 2);  // P1, Z2
    half_t* hD1 = (half_t*)carve((size_t)N * 64 * 2);   // P3
    half_t* hD2 = (half_t*)carve((size_t)N * 64 * 2);   // Z3
    half_t* hE  = (half_t*)carve((size_t)N * 64 * 2);   // P4 padded
    (void)n_in; (void)out_size; (void)ws_size;

    // single memset covers colidx pad (from colidx+E) through stats (adjacent carves)
    {
        char* z0 = (char*)(colidx + E);
        char* z1 = (char*)stats + 3 * 512 * 4;
        hipMemsetAsync(z0, 0, (size_t)(z1 - z0), stream);
    }

    // CSR build
    csr_hist_kernel<<<NB, 256, 0, stream>>>(ei + E, hcnt, E, B, NB, chunk);
    csr_bscan_kernel<<<B, 256, 0, stream>>>(hcnt, btot, NB);
    csr_ebase_kernel<<<1, 256, 0, stream>>>(btot, edge_base, row_ptr, B, E, N);
    csr_part_kernel<<<NB, 256, 0, stream>>>(ei, hcnt, edge_base, ebuf, E, B, NB, chunk);
    csr_fill_kernel<<<B, 256, 0, stream>>>(ebuf, edge_base, row_ptr, dinv, colidx, N);

    // weights transpose + x->fp16 in ONE launch (xh into hB)
    int total4 = N * 128 / 4;
    int prep_blocks = WT_BLOCKS + (total4 + 255) / 256;
    prep_kernel<<<prep_blocks, 256, 0, stream>>>(W1, W2, W3, W4, W1t, W2t, W3t, W4t,
                                                 x, hB, total4);

    int nTiles = (N + 63) / 64;
    int ab = (N + 3) / 4;

    // L1: aggregate xh, GEMM1 (col-split y=2), stats2<256>
    aggh128_kernel<<<ab, 256, 0, stream>>>(hB, hC, row_ptr, colidx, dinv, N);
    mgemm_kernel<128, 8, false><<<dim3(512, 2), 256, 0, stream>>>(
        hC, W1t, nullptr, nullptr, nullptr, nullptr, hA, N, 256, nTiles);
    stats2_kernel<256><<<512, 256, 0, stream>>>(hA, stats, N);

    // L2: GEMM2 (BN1+PReLU coeffs in-kernel) -> P2, aggregate -> Z2, stats2
    mgemm_kernel<256, 4, true><<<dim3(512, 2), 256, 0, stream>>>(
        hA, W2t, stats, g1, be1, pa, hB, N, 128, nTiles);
    aggh128_kernel<<<ab, 256, 0, stream>>>(hB, hC, row_ptr, colidx, dinv, N);
    stats2_kernel<128><<<512, 256, 0, stream>>>(hC, stats + 512, N);

    // L3: GEMM3 (BN2 fused) -> P3, aggregate -> Z3, stats2
    mgemm_kernel<128, 4, true><<<nTiles, 256, 0, stream>>>(
        hC, W3t, stats + 512, g2, be2, pa, hD1, N, 64, nTiles);
    aggh64_kernel<<<(N + 7) / 8, 256, 0, stream>>>(hD1, hD2, row_ptr, colidx, dinv, N);
    stats2_kernel<64><<<512, 256, 0, stream>>>(hD2, stats + 1024, N);

    // L4: GEMM4 (BN3 fused) -> P4 padded, aggregate + b4 + log_softmax -> out
    mgemm_kernel<64, 4, true><<<nTiles, 256, 0, stream>>>(
        hD2, W4t, stats + 1024, g3, be3, pa, hE, N, 64, nTiles);
    aggsm64_kernel<<<(N + 7) / 8, 256, 0, stream>>>(hE, (float*)d_out, row_ptr, colidx,
                                                    dinv, b4, N);
}

// Round 20
// 257.739 us; speedup vs baseline: 1.3946x; 1.0008x over previous
//
#include <hip/hip_runtime.h>
#include <cstdint>
#include <cmath>

typedef _Float16 half_t;
typedef _Float16 h2 __attribute__((ext_vector_type(2)));
typedef _Float16 h8 __attribute__((ext_vector_type(8)));
typedef float f4 __attribute__((ext_vector_type(4)));

// ================= CSR build: bucketed radix partition by dst>>8 =================

__global__ __launch_bounds__(256) void csr_hist_kernel(const int* __restrict__ ei_dst,
                                                       int* __restrict__ hcnt,
                                                       int E, int B, int NB, int chunk) {
    __shared__ int hist[256];
    int t = threadIdx.x;
    hist[t] = 0;
    __syncthreads();
    int base = blockIdx.x * chunk;
    int lim = min(base + chunk, E);
    for (int e = base + t; e < lim; e += 256) {
        int dst = ei_dst[e];
        atomicAdd(&hist[dst >> 8], 1);
    }
    __syncthreads();
    if (t < B) hcnt[t * NB + blockIdx.x] = hist[t];
}

__global__ __launch_bounds__(256) void csr_bscan_kernel(int* __restrict__ hcnt,
                                                        int* __restrict__ btot, int NB) {
    __shared__ int sh[256];
    int b = blockIdx.x, t = threadIdx.x;
    int v = (t < NB) ? hcnt[b * NB + t] : 0;
    sh[t] = v;
    __syncthreads();
    for (int off = 1; off < 256; off <<= 1) {
        int u = (t >= off) ? sh[t - off] : 0;
        __syncthreads();
        sh[t] += u;
        __syncthreads();
    }
    if (t < NB) hcnt[b * NB + t] = sh[t] - v;
    if (t == 255) btot[b] = sh[255];
}

__global__ __launch_bounds__(256) void csr_ebase_kernel(const int* __restrict__ btot,
                                                        int* __restrict__ edge_base,
                                                        int* __restrict__ row_ptr,
                                                        int B, int E, int n) {
    __shared__ int sh[256];
    int t = threadIdx.x;
    int v = (t < B) ? btot[t] : 0;
    sh[t] = v;
    __syncthreads();
    for (int off = 1; off < 256; off <<= 1) {
        int u = (t >= off) ? sh[t - off] : 0;
        __syncthreads();
        sh[t] += u;
        __syncthreads();
    }
    if (t < B) edge_base[t] = sh[t] - v;
    if (t == 0) {
        edge_base[B] = E;
        row_ptr[n] = E;
    }
}

__global__ __launch_bounds__(256) void csr_part_kernel(const int* __restrict__ ei,
                                                       const int* __restrict__ hcnt,
                                                       const int* __restrict__ edge_base,
                                                       unsigned int* __restrict__ ebuf,
                                                       int E, int B, int NB, int chunk) {
    __shared__ int lcur[256];
    int t = threadIdx.x;
    if (t < B) lcur[t] = edge_base[t] + hcnt[t * NB + blockIdx.x];
    __syncthreads();
    int base = blockIdx.x * chunk;
    int lim = min(base + chunk, E);
    for (int e = base + t; e < lim; e += 256) {
        int src = ei[e];
        int dst = ei[E + e];
        int b = dst >> 8;
        int pos = atomicAdd(&lcur[b], 1);
        ebuf[pos] = ((unsigned int)(dst & 255) << 16) | (unsigned int)src;
    }
}

__global__ __launch_bounds__(256) void csr_fill_kernel(const unsigned int* __restrict__ ebuf,
                                                       const int* __restrict__ edge_base,
                                                       int* __restrict__ row_ptr,
                                                       float* __restrict__ dinv,
                                                       unsigned short* __restrict__ colidx,
                                                       int n) {
    __shared__ int cnt[256];
    __shared__ int sc[256];
    __shared__ int cur[256];
    int b = blockIdx.x;
    int t = threadIdx.x;
    int seg_beg = edge_base[b];
    int seg_end = edge_base[b + 1];
    cnt[t] = 0;
    __syncthreads();
    for (int e = seg_beg + t; e < seg_end; e += 256)
        atomicAdd(&cnt[ebuf[e] >> 16], 1);
    __syncthreads();
    sc[t] = cnt[t];
    __syncthreads();
    for (int off = 1; off < 256; off <<= 1) {
        int u = (t >= off) ? sc[t - off] : 0;
        __syncthreads();
        sc[t] += u;
        __syncthreads();
    }
    int excl = seg_beg + sc[t] - cnt[t];
    int node = (b << 8) + t;
    if (node < n) {
        row_ptr[node] = excl;
        dinv[node] = rsqrtf((float)cnt[t] + 1.0f);
    }
    cur[t] = excl;
    __syncthreads();
    for (int e = seg_beg + t; e < seg_end; e += 256) {
        unsigned int p = ebuf[e];
        int pos = atomicAdd(&cur[p >> 16], 1);
        colidx[pos] = (unsigned short)(p & 0xffff);
    }
}

// ---- prep: weight transposes (blocks 0..303) + x->fp16 (remaining blocks), one launch ----

#define WT_BLOCKS 304  // ceil(77824/256)

__global__ __launch_bounds__(256) void prep_kernel(const float* __restrict__ W1,
                                                   const float* __restrict__ W2,
                                                   const float* __restrict__ W3,
                                                   const float* __restrict__ W4,
                                                   half_t* __restrict__ W1t,
                                                   half_t* __restrict__ W2t,
                                                   half_t* __restrict__ W3t,
                                                   half_t* __restrict__ W4t,
                                                   const float* __restrict__ x,
                                                   half_t* __restrict__ xh, int total4) {
    if (blockIdx.x < WT_BLOCKS) {
        int idx = blockIdx.x * 256 + threadIdx.x;
        if (idx < 32768) {
            int n = idx >> 7, k = idx & 127;
            W1t[idx] = (half_t)W1[k * 256 + n];
        } else if (idx < 65536) {
            int r = idx - 32768;
            int n = r >> 8, k = r & 255;
            W2t[r] = (half_t)W2[k * 128 + n];
        } else if (idx < 73728) {
            int r = idx - 65536;
            int n = r >> 7, k = r & 127;
            W3t[r] = (half_t)W3[k * 64 + n];
        } else if (idx < 77824) {
            int r = idx - 73728;
            int n = r >> 6, k = r & 63;
            W4t[r] = (n < 40) ? (half_t)W4[k * 40 + n] : (half_t)0.f;
        }
    } else {
        int i = (blockIdx.x - WT_BLOCKS) * 256 + threadIdx.x;
        if (i < total4) {
            float4 v = *(const float4*)&x[i * 4];
            half_t* p = xh + (size_t)i * 4;
            p[0] = (half_t)v.x; p[1] = (half_t)v.y; p[2] = (half_t)v.z; p[3] = (half_t)v.w;
        }
    }
}

// ------- aggregation (fp16): out[d] = dinv[d]*(sum dinv[s]*in[s] + dinv[d]*in[d]) --------
// Masked unroll-8 (colidx padded by 16 zeros); gather from fp16 only (round 13);
// no fused stats in big grids (round 12, G12).

// F=128: one 64-lane wave per node (row 256B), 4 nodes/block.
__global__ __launch_bounds__(256) void aggh128_kernel(const half_t* __restrict__ in,
                                                      half_t* __restrict__ out,
                                                      const int* __restrict__ row_ptr,
                                                      const unsigned short* __restrict__ colidx,
                                                      const float* __restrict__ dinv, int n) {
    int node = blockIdx.x * 4 + (threadIdx.x >> 6);
    if (node >= n) return;
    int c = threadIdx.x & 63;
    float dv = dinv[node];
    h2 self = *(const h2*)(in + (size_t)node * 128 + 2 * c);
    float acc0 = dv * (float)self[0], acc1 = dv * (float)self[1];
    int beg = row_ptr[node], end = row_ptr[node + 1];
    for (int k = beg; k < end; k += 8) {
        int idx[8]; float w[8]; h2 v[8];
#pragma unroll
        for (int j = 0; j < 8; ++j) idx[j] = colidx[k + j];
#pragma unroll
        for (int j = 0; j < 8; ++j) w[j] = (k + j < end) ? dinv[idx[j]] : 0.f;
#pragma unroll
        for (int j = 0; j < 8; ++j) v[j] = *(const h2*)(in + (size_t)idx[j] * 128 + 2 * c);
#pragma unroll
        for (int j = 0; j < 8; ++j) {
            acc0 = fmaf(w[j], (float)v[j][0], acc0);
            acc1 = fmaf(w[j], (float)v[j][1], acc1);
        }
    }
    h2 r;
    r[0] = (half_t)(dv * acc0);
    r[1] = (half_t)(dv * acc1);
    *(h2*)(out + (size_t)node * 128 + 2 * c) = r;
}

// F=64: one node per 32-lane half-wave (row = 128B line), 8 nodes/block, h2 loads.
__global__ __launch_bounds__(256) void aggh64_kernel(const half_t* __restrict__ in,
                                                     half_t* __restrict__ out,
                                                     const int* __restrict__ row_ptr,
                                                     const unsigned short* __restrict__ colidx,
                                                     const float* __restrict__ dinv, int n) {
    int node = blockIdx.x * 8 + (threadIdx.x >> 5);
    if (node >= n) return;
    int c = threadIdx.x & 31;
    float dv = dinv[node];
    h2 self = *(const h2*)(in + (size_t)node * 64 + 2 * c);
    float acc0 = dv * (float)self[0], acc1 = dv * (float)self[1];
    int beg = row_ptr[node], end = row_ptr[node + 1];
    for (int k = beg; k < end; k += 8) {
        int idx[8]; float w[8]; h2 v[8];
#pragma unroll
        for (int j = 0; j < 8; ++j) idx[j] = colidx[k + j];
#pragma unroll
        for (int j = 0; j < 8; ++j) w[j] = (k + j < end) ? dinv[idx[j]] : 0.f;
#pragma unroll
        for (int j = 0; j < 8; ++j) v[j] = *(const h2*)(in + (size_t)idx[j] * 64 + 2 * c);
#pragma unroll
        for (int j = 0; j < 8; ++j) {
            acc0 = fmaf(w[j], (float)v[j][0], acc0);
            acc1 = fmaf(w[j], (float)v[j][1], acc1);
        }
    }
    h2 r;
    r[0] = (half_t)(dv * acc0);
    r[1] = (half_t)(dv * acc1);
    *(h2*)(out + (size_t)node * 64 + 2 * c) = r;
}

// final layer: one node per 32-lane half-wave, aggregate + b4 + log_softmax -> f32 out
__global__ __launch_bounds__(256) void aggsm64_kernel(const half_t* __restrict__ in,
                                                      float* __restrict__ out,
                                                      const int* __restrict__ row_ptr,
                                                      const unsigned short* __restrict__ colidx,
                                                      const float* __restrict__ dinv,
                                                      const float* __restrict__ b4, int n) {
    int node = blockIdx.x * 8 + (threadIdx.x >> 5);
    if (node >= n) return;
    int c = threadIdx.x & 31;
    float dv = dinv[node];
    h2 self = *(const h2*)(in + (size_t)node * 64 + 2 * c);
    float acc0 = dv * (float)self[0], acc1 = dv * (float)self[1];
    int beg = row_ptr[node], end = row_ptr[node + 1];
    for (int k = beg; k < end; k += 8) {
        int idx[8]; float w[8]; h2 v[8];
#pragma unroll
        for (int j = 0; j < 8; ++j) idx[j] = colidx[k + j];
#pragma unroll
        for (int j = 0; j < 8; ++j) w[j] = (k + j < end) ? dinv[idx[j]] : 0.f;
#pragma unroll
        for (int j = 0; j < 8; ++j) v[j] = *(const h2*)(in + (size_t)idx[j] * 64 + 2 * c);
#pragma unroll
        for (int j = 0; j < 8; ++j) {
            acc0 = fmaf(w[j], (float)v[j][0], acc0);
            acc1 = fmaf(w[j], (float)v[j][1], acc1);
        }
    }
    int col0 = 2 * c, col1 = 2 * c + 1;
    float z0 = (col0 < 40) ? (dv * acc0 + b4[col0]) : -INFINITY;
    float z1 = (col1 < 40) ? (dv * acc1 + b4[col1]) : -INFINITY;
    float m = fmaxf(z0, z1);
#pragma unroll
    for (int off = 16; off > 0; off >>= 1) m = fmaxf(m, __shfl_xor(m, off, 32));
    float e0 = (col0 < 40) ? expf(z0 - m) : 0.f;
    float e1 = (col1 < 40) ? expf(z1 - m) : 0.f;
    float s = e0 + e1;
#pragma unroll
    for (int off = 16; off > 0; off >>= 1) s += __shfl_xor(s, off, 32);
    float ls = logf(s);
    if (c < 20) {
        float2 r = make_float2(z0 - m - ls, z1 - m - ls);
        *(float2*)(out + (size_t)node * 40 + 2 * c) = r;
    }
}

// ---------------- MFMA GEMM v5: col-split LDS weights + bank-pad + BNC (no stats) -------
// Round 20: GEMM1/2 col-split deepened to y=4 -> ~17-19KB LDS -> 8 blocks/CU (was 4).

template <int K, int NT, bool BNC>
__global__ __launch_bounds__(256) void mgemm_kernel(const half_t* __restrict__ A,
                                                    const half_t* __restrict__ Wt,  // [cols][K]
                                                    const float* __restrict__ bn_stats,
                                                    const float* __restrict__ g,
                                                    const float* __restrict__ be,
                                                    const float* __restrict__ pa,
                                                    half_t* __restrict__ C,
                                                    int M, int Nc, int nTiles) {
    constexpr int NR = NT * 16;
    constexpr int CH = K / 8;
    constexpr int LOG_CH = (CH == 8) ? 3 : (CH == 16 ? 4 : 5);
    constexpr int CSTRIDE = NR + 1;  // +16B bank pad
    __shared__ half_t wlds[CH * CSTRIDE * 8];
    __shared__ float sc_l[K], of_l[K];

    int t = threadIdx.x;
    int colbase = blockIdx.y * NR;
    for (int idx = t; idx < NR * CH; idx += 256) {
        int row = idx >> LOG_CH;
        int c = idx & (CH - 1);
        *(h8*)(wlds + ((size_t)c * CSTRIDE + row) * 8) =
            *(const h8*)(Wt + (size_t)(colbase + row) * K + c * 8);
    }
    if (BNC && t < K) {
        float inv_n = 1.0f / (float)M;
        float mean = bn_stats[t] * inv_n;
        float var = bn_stats[256 + t] * inv_n - mean * mean;
        float rstd = rsqrtf(var + 1e-5f);
        float s = g[t] * rstd;
        sc_l[t] = s;
        of_l[t] = be[t] - mean * s;
    }
    int wave = t >> 6;
    int lane = t & 63;
    int l16 = lane & 15, kgrp = lane >> 4;
    float alpha = BNC ? pa[0] : 0.f;
    __syncthreads();

    for (int tile = blockIdx.x; tile < nTiles; tile += gridDim.x) {
        int r0 = tile * 64 + wave * 16;
        int arow = r0 + l16;
        bool rowok = (arow < M);
        const half_t* Ap = A + (size_t)arow * K + kgrp * 8;
        h8 af[K / 32];
#pragma unroll
        for (int kk = 0; kk < K / 32; ++kk) {
            h8 v;
            if (rowok) {
                v = *(const h8*)(Ap + kk * 32);
            } else {
#pragma unroll
                for (int j = 0; j < 8; ++j) v[j] = (half_t)0.f;
            }
            if (BNC) {
                int kb = kk * 32 + kgrp * 8;
#pragma unroll
                for (int j = 0; j < 8; ++j) {
                    float u = (float)v[j] * sc_l[kb + j] + of_l[kb + j];
                    u = (u >= 0.f) ? u : alpha * u;
                    v[j] = (half_t)u;
                }
            }
            af[kk] = v;
        }

        for (int nt = 0; nt < NT; ++nt) {
            f4 acc = {0.f, 0.f, 0.f, 0.f};
#pragma unroll
            for (int kk = 0; kk < K / 32; ++kk) {
                h8 bf = *(const h8*)(wlds +
                                     ((size_t)(kk * 4 + kgrp) * CSTRIDE + nt * 16 + l16) * 8);
                acc = __builtin_amdgcn_mfma_f32_16x16x32_f16(af[kk], bf, acc, 0, 0, 0);
            }
            int col = colbase + nt * 16 + l16;
            if (col < Nc) {
#pragma unroll
                for (int j = 0; j < 4; ++j) {
                    int row = r0 + kgrp * 4 + j;
                    if (row < M) C[(size_t)row * Nc + col] = (half_t)acc[j];
                }
            }
        }
    }
}

// ---------------- BatchNorm stats (dedicated 512-block, LDS-reduced, atomics) ----------

template <int F>
__global__ __launch_bounds__(256) void stats2_kernel(const half_t* __restrict__ z,
                                                     float* __restrict__ sums, int n) {
    constexpr int CB = F / 8;
    constexpr int RG = 256 / CB;
    __shared__ float red[256][16];
    int t = threadIdx.x;
    int cb = t % CB;
    int rg = t / CB;
    float sm[8], sq[8];
#pragma unroll
    for (int j = 0; j < 8; ++j) { sm[j] = 0.f; sq[j] = 0.f; }
    for (int r = blockIdx.x * RG + rg; r < n; r += gridDim.x * RG) {
        h8 v = *(const h8*)(z + (size_t)r * F + cb * 8);
#pragma unroll
        for (int j = 0; j < 8; ++j) {
            float f = (float)v[j];
            sm[j] += f;
            sq[j] = fmaf(f, f, sq[j]);
        }
    }
#pragma unroll
    for (int j = 0; j < 8; ++j) { red[t][j] = sm[j]; red[t][8 + j] = sq[j]; }
    __syncthreads();
    for (int o = t; o < 2 * F; o += 256) {
        int c = o % F, kind = o / F;
        int cbo = c >> 3, ci = (c & 7) + kind * 8;
        float v = 0.f;
#pragma unroll
        for (int g = 0; g < RG; ++g) v += red[g * CB + cbo][ci];
        atomicAdd(&sums[kind * 256 + c], v);
    }
}

// ---------------- launch ----------------

extern "C" void kernel_launch(void* const* d_in, const int* in_sizes, int n_in,
                              void* d_out, int out_size, void* d_ws, size_t ws_size,
                              hipStream_t stream) {
    const float* x   = (const float*)d_in[0];
    const int*   ei  = (const int*)d_in[1];
    const float* W1  = (const float*)d_in[2];
    const float* g1  = (const float*)d_in[4];
    const float* be1 = (const float*)d_in[5];
    const float* W2  = (const float*)d_in[6];
    const float* g2  = (const float*)d_in[8];
    const float* be2 = (const float*)d_in[9];
    const float* W3  = (const float*)d_in[10];
    const float* g3  = (const float*)d_in[12];
    const float* be3 = (const float*)d_in[13];
    const float* W4  = (const float*)d_in[14];
    const float* b4  = (const float*)d_in[15];
    const float* pa  = (const float*)d_in[16];
    // b1,b2,b3 dropped: constants before BatchNorm cancel exactly in mean subtraction.

    int N = in_sizes[0] / 128;
    int E = in_sizes[1] / 2;
    int B = (N + 255) >> 8;
    int chunk = (((E + 255) / 256) + 255) & ~255;
    int NB = (E + chunk - 1) / chunk;

    char* ws = (char*)d_ws;
    size_t off = 0;
    auto carve = [&](size_t bytes) -> char* {
        char* p = ws + off;
        off += (bytes + 255) & ~(size_t)255;
        return p;
    };
    float*          dinv      = (float*)carve((size_t)N * 4);
    int*            row_ptr   = (int*)carve((size_t)(N + 1) * 4);
    int*            hcnt      = (int*)carve((size_t)B * NB * 4);
    int*            btot      = (int*)carve((size_t)B * 4);
    int*            edge_base = (int*)carve((size_t)(B + 1) * 4);
    unsigned int*   ebuf      = (unsigned int*)carve((size_t)E * 4);
    unsigned short* colidx    = (unsigned short*)carve((size_t)(E + 16) * 2);
    float*          stats     = (float*)carve(3 * 512 * 4);
    half_t* W1t = (half_t*)carve((size_t)256 * 128 * 2);
    half_t* W2t = (half_t*)carve((size_t)128 * 256 * 2);
    half_t* W3t = (half_t*)carve((size_t)64 * 128 * 2);
    half_t* W4t = (half_t*)carve((size_t)64 * 64 * 2);
    half_t* hA  = (half_t*)carve((size_t)N * 256 * 2);  // Z1
    half_t* hB  = (half_t*)carve((size_t)N * 128 * 2);  // xh, P2
    half_t* hC  = (half_t*)carve((size_t)N * 128 * 2);  // P1, Z2
    half_t* hD1 = (half_t*)carve((size_t)N * 64 * 2);   // P3
    half_t* hD2 = (half_t*)carve((size_t)N * 64 * 2);   // Z3
    half_t* hE  = (half_t*)carve((size_t)N * 64 * 2);   // P4 padded
    (void)n_in; (void)out_size; (void)ws_size;

    // single memset covers colidx pad (from colidx+E) through stats (adjacent carves)
    {
        char* z0 = (char*)(colidx + E);
        char* z1 = (char*)stats + 3 * 512 * 4;
        hipMemsetAsync(z0, 0, (size_t)(z1 - z0), stream);
    }

    // CSR build
    csr_hist_kernel<<<NB, 256, 0, stream>>>(ei + E, hcnt, E, B, NB, chunk);
    csr_bscan_kernel<<<B, 256, 0, stream>>>(hcnt, btot, NB);
    csr_ebase_kernel<<<1, 256, 0, stream>>>(btot, edge_base, row_ptr, B, E, N);
    csr_part_kernel<<<NB, 256, 0, stream>>>(ei, hcnt, edge_base, ebuf, E, B, NB, chunk);
    csr_fill_kernel<<<B, 256, 0, stream>>>(ebuf, edge_base, row_ptr, dinv, colidx, N);

    // weights transpose + x->fp16 in ONE launch (xh into hB)
    int total4 = N * 128 / 4;
    int prep_blocks = WT_BLOCKS + (total4 + 255) / 256;
    prep_kernel<<<prep_blocks, 256, 0, stream>>>(W1, W2, W3, W4, W1t, W2t, W3t, W4t,
                                                 x, hB, total4);

    int nTiles = (N + 63) / 64;
    int ab = (N + 3) / 4;

    // L1: aggregate xh, GEMM1 (col-split y=4, 8 blocks/CU), stats2<256>
    aggh128_kernel<<<ab, 256, 0, stream>>>(hB, hC, row_ptr, colidx, dinv, N);
    mgemm_kernel<128, 4, false><<<dim3(512, 4), 256, 0, stream>>>(
        hC, W1t, nullptr, nullptr, nullptr, nullptr, hA, N, 256, nTiles);
    stats2_kernel<256><<<512, 256, 0, stream>>>(hA, stats, N);

    // L2: GEMM2 (BN1+PReLU coeffs in-kernel, y=4) -> P2, aggregate -> Z2, stats2
    mgemm_kernel<256, 2, true><<<dim3(512, 4), 256, 0, stream>>>(
        hA, W2t, stats, g1, be1, pa, hB, N, 128, nTiles);
    aggh128_kernel<<<ab, 256, 0, stream>>>(hB, hC, row_ptr, colidx, dinv, N);
    stats2_kernel<128><<<512, 256, 0, stream>>>(hC, stats + 512, N);

    // L3: GEMM3 (BN2 fused) -> P3, aggregate -> Z3, stats2
    mgemm_kernel<128, 4, true><<<nTiles, 256, 0, stream>>>(
        hC, W3t, stats + 512, g2, be2, pa, hD1, N, 64, nTiles);
    aggh64_kernel<<<(N + 7) / 8, 256, 0, stream>>>(hD1, hD2, row_ptr, colidx, dinv, N);
    stats2_kernel<64><<<512, 256, 0, stream>>>(hD2, stats + 1024, N);

    // L4: GEMM4 (BN3 fused) -> P4 padded, aggregate + b4 + log_softmax -> out
    mgemm_kernel<64, 4, true><<<nTiles, 256, 0, stream>>>(
        hD2, W4t, stats + 1024, g3, be3, pa, hE, N, 64, nTiles);
    aggsm64_kernel<<<(N + 7) / 8, 256, 0, stream>>>(hE, (float*)d_out, row_ptr, colidx,
                                                    dinv, b4, N);
}